// Round 1
// baseline (411.952 us; speedup 1.0000x reference)
//
#include <hip/hip_runtime.h>

// ---------------------------------------------------------------------------
// Attention layer: qkv proj -> RoPE -> concat KV cache -> softmax attn -> out proj
// B=4 Sq=1024 Skv_cache=1024 H=16 D=128 D_MODEL=2048
// Strategy: bf16 MFMA everywhere (2% absmax tolerance), m97-style GEMMs,
// flash attention with swapped QK^T and XOR-swizzled LDS.
// ---------------------------------------------------------------------------

typedef __bf16 bf16x8 __attribute__((ext_vector_type(8)));
typedef float f32x4 __attribute__((ext_vector_type(4)));
typedef unsigned short u16x8 __attribute__((ext_vector_type(8)));
typedef unsigned short u16x4 __attribute__((ext_vector_type(4)));

__device__ __forceinline__ float b2f(unsigned short u) {
  return __builtin_bit_cast(float, (unsigned int)u << 16);
}
__device__ __forceinline__ unsigned short f2b(float f) {
  unsigned int x = __builtin_bit_cast(unsigned int, f);
  x += 0x7fffu + ((x >> 16) & 1u);   // RNE (finite values only)
  return (unsigned short)(x >> 16);
}
__device__ __forceinline__ void gload_lds16(const void* g, void* l) {
  __builtin_amdgcn_global_load_lds(
      (__attribute__((address_space(1))) void*)(g),
      (__attribute__((address_space(3))) void*)(l), 16, 0, 0);
}

// ---------------- trig table: cos/sin of (1024+s)*theta^(-i/64) ------------
__global__ void build_trig(float* __restrict__ cs, float* __restrict__ sn) {
  int idx = blockIdx.x * 256 + threadIdx.x;   // 65536 = 1024 s * 64 i
  int s = idx >> 6, i = idx & 63;
  float inv = exp2f(-(float)i * (13.287712379549449f / 64.0f)); // 10000^(-i/64)
  float ang = (float)(1024 + s) * inv;
  cs[idx] = cosf(ang);
  sn[idx] = sinf(ang);
}

// ---------------- f32 -> bf16 convert (8/thread) ---------------------------
__global__ void conv_bf16(const float* __restrict__ in, unsigned short* __restrict__ out) {
  size_t i = ((size_t)blockIdx.x * 256 + threadIdx.x) * 8;
  float4 a = *(const float4*)(in + i);
  float4 b = *(const float4*)(in + i + 4);
  u16x8 v;
  v[0] = f2b(a.x); v[1] = f2b(a.y); v[2] = f2b(a.z); v[3] = f2b(a.w);
  v[4] = f2b(b.x); v[5] = f2b(b.y); v[6] = f2b(b.z); v[7] = f2b(b.w);
  *(u16x8*)(out + i) = v;
}

// ---------------- transposed convert: in[R][C] f32 -> out[C][R] bf16 -------
__global__ __launch_bounds__(256) void transpose_conv(
    const float* __restrict__ in, unsigned short* __restrict__ out, int R, int C) {
  __shared__ float tile[32][33];
  int c0 = blockIdx.x * 32, r0 = blockIdx.y * 32;
  int tx = threadIdx.x & 31, ty = threadIdx.x >> 5;   // 32 x 8
#pragma unroll
  for (int j = 0; j < 4; ++j)
    tile[ty + j * 8][tx] = in[(size_t)(r0 + ty + j * 8) * C + c0 + tx];
  __syncthreads();
#pragma unroll
  for (int j = 0; j < 4; ++j)
    out[(size_t)(c0 + ty + j * 8) * R + r0 + tx] = f2b(tile[tx][ty + j * 8]);
}

// ---------------- cache_k f32 -> K_full[:, :1024] bf16 ---------------------
__global__ void copy_k(const float* __restrict__ ck, unsigned short* __restrict__ Kf) {
  size_t idx = ((size_t)blockIdx.x * 256 + threadIdx.x) * 4;  // over 64*1024*128
  size_t bh = idx >> 17, rem = idx & 131071;                  // 1024*128 = 2^17
  float4 a = *(const float4*)(ck + idx);
  u16x4 v;
  v[0] = f2b(a.x); v[1] = f2b(a.y); v[2] = f2b(a.z); v[3] = f2b(a.w);
  *(u16x4*)(Kf + bh * 262144 + rem) = v;                      // 2048*128 row block
}

// ---------------- RoPE q,k from qkv; q scaled by 1/sqrt(128) ---------------
__global__ __launch_bounds__(256) void rope_qk(
    const unsigned short* __restrict__ qkv, const float* __restrict__ cs,
    const float* __restrict__ sn, unsigned short* __restrict__ Qb,
    unsigned short* __restrict__ Kf) {
  int row = blockIdx.x;                 // b*1024 + s
  int b = row >> 10, s = row & 1023;
#pragma unroll
  for (int it = 0; it < 4; ++it) {
    int item = it * 256 + threadIdx.x;  // 16 heads * 64 pairs
    int h = item >> 6, i = item & 63;
    const unsigned short* base = qkv + (size_t)row * 6144 + h * 384;
    float q1 = b2f(base[i]),       q2 = b2f(base[64 + i]);
    float k1 = b2f(base[128 + i]), k2 = b2f(base[192 + i]);
    float c = cs[s * 64 + i], sv = sn[s * 64 + i];
    const float scale = 0.08838834764831845f;   // 1/sqrt(128)
    size_t bh = (size_t)(b * 16 + h);
    unsigned short* qd = Qb + (bh * 1024 + s) * 128;
    qd[i]      = f2b((q1 * c - q2 * sv) * scale);
    qd[64 + i] = f2b((q2 * c + q1 * sv) * scale);
    unsigned short* kd = Kf + (bh * 2048 + 1024 + s) * 128;
    kd[i]      = f2b(k1 * c - k2 * sv);
    kd[64 + i] = f2b(k2 * c + k1 * sv);
  }
}

// ---------------- V^T build: V_t[b][h][d][s], s<1024 from cache, else qkv --
__global__ __launch_bounds__(256) void build_vt(
    const float* __restrict__ cv, const unsigned short* __restrict__ qkv,
    unsigned short* __restrict__ Vt) {
  __shared__ float tile[32][33];
  int bhid = blockIdx.z;
  int s0 = blockIdx.x * 32, d0 = blockIdx.y * 32;
  int tx = threadIdx.x & 31, ty = threadIdx.x >> 5;
  int b = bhid >> 4, h = bhid & 15;
#pragma unroll
  for (int j = 0; j < 4; ++j) {
    int s = s0 + ty + j * 8, d = d0 + tx;
    float v;
    if (s < 1024) v = cv[((size_t)bhid * 1024 + s) * 128 + d];
    else v = b2f(qkv[((size_t)b * 1024 + (s - 1024)) * 6144 + h * 384 + 256 + d]);
    tile[ty + j * 8][tx] = v;
  }
  __syncthreads();
#pragma unroll
  for (int j = 0; j < 4; ++j) {
    int d = d0 + ty + j * 8, s = s0 + tx;
    Vt[((size_t)bhid * 128 + d) * 2048 + s] = f2b(tile[tx][ty + j * 8]);
  }
}

// ---------------- GEMM: C[M][N] = A[M][K] * B^T  (B given as [N][K]) -------
// m97 structure: 128x128 tile, BK=32, 4 waves (2x2), 4x4 16x16x32 frags/wave.
template <int M, int N, int K, bool OUT_BF16>
__global__ __launch_bounds__(256) void gemm_bt(
    const unsigned short* __restrict__ A, const unsigned short* __restrict__ B,
    void* __restrict__ Cout) {
  __shared__ __align__(16) unsigned short As[128 * 32];
  __shared__ __align__(16) unsigned short Bs[128 * 32];
  constexpr int NT = N / 128;
  int bid = blockIdx.x;
  int tm = bid / NT, tn = bid % NT;
  int tid = threadIdx.x;
  int lane = tid & 63, wave = tid >> 6;
  int wr = (wave >> 1) * 64, wc = (wave & 1) * 64;
  int l15 = lane & 15, g = lane >> 4;

  f32x4 acc[4][4] = {};
  const unsigned short* Ab = A + (size_t)tm * 128 * K;
  const unsigned short* Bb = B + (size_t)tn * 128 * K;

  for (int k0 = 0; k0 < K; k0 += 32) {
#pragma unroll
    for (int is = 0; is < 2; ++is) {
      int p = tid * 16 + is * 4096;          // byte offset in 8KB tile
      int row = p >> 6, kb = p & 63;
      gload_lds16(Ab + (size_t)row * K + k0 + (kb >> 1),
                  (char*)As + is * 4096 + (tid & 192) * 16);
      gload_lds16(Bb + (size_t)row * K + k0 + (kb >> 1),
                  (char*)Bs + is * 4096 + (tid & 192) * 16);
    }
    __syncthreads();
    bf16x8 af[4], bfr[4];
#pragma unroll
    for (int m = 0; m < 4; ++m)
      af[m] = *(const bf16x8*)((const char*)As + (wr + m * 16 + l15) * 64 + g * 16);
#pragma unroll
    for (int n = 0; n < 4; ++n)
      bfr[n] = *(const bf16x8*)((const char*)Bs + (wc + n * 16 + l15) * 64 + g * 16);
#pragma unroll
    for (int m = 0; m < 4; ++m)
#pragma unroll
      for (int n = 0; n < 4; ++n)
        acc[m][n] = __builtin_amdgcn_mfma_f32_16x16x32_bf16(af[m], bfr[n], acc[m][n], 0, 0, 0);
    __syncthreads();
  }
#pragma unroll
  for (int m = 0; m < 4; ++m) {
    int row0 = tm * 128 + wr + m * 16 + g * 4;
#pragma unroll
    for (int n = 0; n < 4; ++n) {
      int col = tn * 128 + wc + n * 16 + l15;
#pragma unroll
      for (int r = 0; r < 4; ++r) {
        size_t off = (size_t)(row0 + r) * N + col;
        if constexpr (OUT_BF16) ((unsigned short*)Cout)[off] = f2b(acc[m][n][r]);
        else ((float*)Cout)[off] = acc[m][n][r];
      }
    }
  }
}

// ---------------- Flash attention ------------------------------------------
// grid = (B*H) * (1024/64); 4 waves, each wave owns 16 q rows.
// S^T = K*Q^T (q per-lane = lane&15); P^T via LDS; out^T = V^T*P^T.
__global__ __launch_bounds__(256) void attn_kernel(
    const unsigned short* __restrict__ Qb,   // [64][1024][128]
    const unsigned short* __restrict__ Kf,   // [64][2048][128]
    const unsigned short* __restrict__ Vt,   // [64][128][2048]
    unsigned short* __restrict__ Out) {      // [4096][2048] = [b][s][h*128+d]
  __shared__ __align__(16) unsigned short Ks[64 * 128];   // 16KB, XOR-swizzled
  __shared__ __align__(16) unsigned short Vs[128 * 64];   // 16KB, XOR-swizzled
  __shared__ __align__(16) unsigned short Ps[4][16 * 72]; // per-wave P^T, pad 72

  int bid = blockIdx.x;
  int bh = bid >> 4, qt = bid & 15;
  int tid = threadIdx.x, lane = tid & 63, wave = tid >> 6;
  int l15 = lane & 15, g = lane >> 4;
  int qrow = qt * 64 + wave * 16 + l15;

  bf16x8 qf[4];
  const unsigned short* qp = Qb + ((size_t)bh * 1024 + qrow) * 128;
#pragma unroll
  for (int kk = 0; kk < 4; ++kk)
    qf[kk] = *(const bf16x8*)(qp + kk * 32 + g * 8);

  float mrun = -1e30f, lsum = 0.f;
  f32x4 acc[8] = {};
  const unsigned short* Kbase = Kf + (size_t)bh * 2048 * 128;
  const unsigned short* Vbase = Vt + (size_t)bh * 128 * 2048;

  for (int kv0 = 0; kv0 < 2048; kv0 += 64) {
    // stage K[64][128] and V^T[128][64], XOR-swizzle via pre-swizzled source
#pragma unroll
    for (int is = 0; is < 4; ++is) {
      int p = tid * 16 + is * 4096;
      int lgk = p ^ (((p >> 8) & 7) << 4);          // K rows = 256B
      int kv = lgk >> 8, db = lgk & 255;
      gload_lds16(Kbase + (size_t)(kv0 + kv) * 128 + (db >> 1),
                  (char*)Ks + is * 4096 + (tid & 192) * 16);
      int lgv = p ^ (((p >> 7) & 7) << 4);          // V^T rows = 128B
      int d = lgv >> 7, sb = lgv & 127;
      gload_lds16(Vbase + (size_t)d * 2048 + kv0 + (sb >> 1),
                  (char*)Vs + is * 4096 + (tid & 192) * 16);
    }
    __syncthreads();

    // S^T tiles: 4 x (16 kv x 16 q)
    f32x4 st[4] = {};
#pragma unroll
    for (int kk = 0; kk < 4; ++kk) {
#pragma unroll
      for (int t = 0; t < 4; ++t) {
        int kv = t * 16 + l15;
        int bo = (kv * 256 + kk * 64 + g * 16) ^ ((kv & 7) << 4);
        bf16x8 a = *(const bf16x8*)((const char*)Ks + bo);
        st[t] = __builtin_amdgcn_mfma_f32_16x16x32_bf16(a, qf[kk], st[t], 0, 0, 0);
      }
    }

    // online softmax; lane's q = l15, lane holds kv = t*16 + g*4 + r
    float pmax = -1e30f;
#pragma unroll
    for (int t = 0; t < 4; ++t)
#pragma unroll
      for (int r = 0; r < 4; ++r) pmax = fmaxf(pmax, st[t][r]);
    pmax = fmaxf(pmax, __shfl_xor(pmax, 16));
    pmax = fmaxf(pmax, __shfl_xor(pmax, 32));
    float mnew = fmaxf(mrun, pmax);
    float corr = exp2f((mrun - mnew) * 1.44269504f);
    float psum = 0.f;
    unsigned int pb[4][4];
#pragma unroll
    for (int t = 0; t < 4; ++t)
#pragma unroll
      for (int r = 0; r < 4; ++r) {
        float pv = exp2f((st[t][r] - mnew) * 1.44269504f);
        psum += pv;
        pb[t][r] = f2b(pv);
      }
    psum += __shfl_xor(psum, 16);
    psum += __shfl_xor(psum, 32);
    lsum = lsum * corr + psum;
    mrun = mnew;
#pragma unroll
    for (int mt = 0; mt < 8; ++mt) acc[mt] *= corr;

    // write P^T to per-wave LDS: Ps[q=l15][kv]
#pragma unroll
    for (int t = 0; t < 4; ++t) {
      uint2 w;
      w.x = pb[t][0] | (pb[t][1] << 16);
      w.y = pb[t][2] | (pb[t][3] << 16);
      *(uint2*)(&Ps[wave][l15 * 72 + t * 16 + g * 4]) = w;
    }

    // out^T += V^T * P^T
#pragma unroll
    for (int k2 = 0; k2 < 2; ++k2) {
      bf16x8 pfr = *(const bf16x8*)(&Ps[wave][l15 * 72 + k2 * 32 + g * 8]);
#pragma unroll
      for (int mt = 0; mt < 8; ++mt) {
        int d = mt * 16 + l15;
        int bo = (d * 128 + k2 * 64 + g * 16) ^ ((d & 7) << 4);
        bf16x8 a = *(const bf16x8*)((const char*)Vs + bo);
        acc[mt] = __builtin_amdgcn_mfma_f32_16x16x32_bf16(a, pfr, acc[mt], 0, 0, 0);
      }
    }
    __syncthreads();
  }

  float inv = 1.f / lsum;
  int b = bh >> 4, h = bh & 15;
  int sq = qt * 64 + wave * 16 + l15;
  unsigned short* orow = Out + ((size_t)(b * 1024 + sq) * 16 + h) * 128;
#pragma unroll
  for (int mt = 0; mt < 8; ++mt) {
    uint2 w;
    w.x = (unsigned)f2b(acc[mt][0] * inv) | ((unsigned)f2b(acc[mt][1] * inv) << 16);
    w.y = (unsigned)f2b(acc[mt][2] * inv) | ((unsigned)f2b(acc[mt][3] * inv) << 16);
    *(uint2*)(orow + mt * 16 + g * 4) = w;
  }
}

// ---------------------------------------------------------------------------
extern "C" void kernel_launch(void* const* d_in, const int* in_sizes, int n_in,
                              void* d_out, int out_size, void* d_ws, size_t ws_size,
                              hipStream_t stream) {
  const float* x       = (const float*)d_in[0];
  const float* cache_k = (const float*)d_in[1];
  const float* cache_v = (const float*)d_in[2];
  const float* w_qkv   = (const float*)d_in[3];
  const float* w_o     = (const float*)d_in[4];
  float* out = (float*)d_out;

  // workspace layout (~176.5 MiB)
  char* W = (char*)d_ws;
  constexpr size_t O_TRIG = 0;                       // 2 * 256KB
  constexpr size_t O_XB   = 524288;                  // 16MB (reused as attn_out)
  constexpr size_t O_WQT  = O_XB  + 16777216;        // 24MB
  constexpr size_t O_WOT  = O_WQT + 25165824;        // 8MB
  constexpr size_t O_QKV  = O_WOT + 8388608;         // 48MB
  constexpr size_t O_QB   = O_QKV + 50331648;        // 16MB
  constexpr size_t O_KF   = O_QB  + 16777216;        // 32MB
  constexpr size_t O_VT   = O_KF  + 33554432;        // 32MB
  float* cs_tab = (float*)(W + O_TRIG);
  float* sn_tab = (float*)(W + O_TRIG + 262144);
  unsigned short* xb   = (unsigned short*)(W + O_XB);
  unsigned short* wqT  = (unsigned short*)(W + O_WQT);
  unsigned short* woT  = (unsigned short*)(W + O_WOT);
  unsigned short* qkv  = (unsigned short*)(W + O_QKV);
  unsigned short* qb   = (unsigned short*)(W + O_QB);
  unsigned short* Kf   = (unsigned short*)(W + O_KF);
  unsigned short* Vt   = (unsigned short*)(W + O_VT);
  unsigned short* attn_out = xb;   // xb dead after gemm1

  build_trig<<<256, 256, 0, stream>>>(cs_tab, sn_tab);
  conv_bf16<<<4096, 256, 0, stream>>>(x, xb);                       // 8.4M elems
  transpose_conv<<<dim3(192, 64), 256, 0, stream>>>(w_qkv, wqT, 2048, 6144);
  transpose_conv<<<dim3(64, 64), 256, 0, stream>>>(w_o, woT, 2048, 2048);
  gemm_bt<4096, 6144, 2048, true><<<32 * 48, 256, 0, stream>>>(xb, wqT, qkv);
  rope_qk<<<4096, 256, 0, stream>>>(qkv, cs_tab, sn_tab, qb, Kf);
  copy_k<<<8192, 256, 0, stream>>>(cache_k, Kf);
  build_vt<<<dim3(64, 4, 64), 256, 0, stream>>>(cache_v, qkv, Vt);
  attn_kernel<<<1024, 256, 0, stream>>>(qb, Kf, Vt, attn_out);
  gemm_bt<4096, 2048, 2048, false><<<32 * 16, 256, 0, stream>>>(attn_out, woT, out);
}

// Round 2
// 375.465 us; speedup vs baseline: 1.0972x; 1.0972x over previous
//
#include <hip/hip_runtime.h>

// ---------------------------------------------------------------------------
// Attention layer: qkv proj -> RoPE -> concat KV cache -> softmax attn -> out proj
// B=4 Sq=1024 Skv_cache=1024 H=16 D=128 D_MODEL=2048
// bf16 MFMA everywhere; m97-style GEMMs; flash attention with swapped QK^T,
// XOR-swizzled LDS, base-2 softmax, cvt_pk packing, defer-max.
// ---------------------------------------------------------------------------

typedef __bf16 bf16x8 __attribute__((ext_vector_type(8)));
typedef float f32x4 __attribute__((ext_vector_type(4)));
typedef unsigned short u16x8 __attribute__((ext_vector_type(8)));
typedef unsigned short u16x4 __attribute__((ext_vector_type(4)));

__device__ __forceinline__ float b2f(unsigned short u) {
  return __builtin_bit_cast(float, (unsigned int)u << 16);
}
__device__ __forceinline__ unsigned short f2b(float f) {
  unsigned int x = __builtin_bit_cast(unsigned int, f);
  x += 0x7fffu + ((x >> 16) & 1u);   // RNE (finite values only)
  return (unsigned short)(x >> 16);
}
__device__ __forceinline__ unsigned int cvt_pk_bf16(float lo, float hi) {
  unsigned int r;
  asm("v_cvt_pk_bf16_f32 %0, %1, %2" : "=v"(r) : "v"(lo), "v"(hi));
  return r;
}
__device__ __forceinline__ void gload_lds16(const void* g, void* l) {
  __builtin_amdgcn_global_load_lds(
      (__attribute__((address_space(1))) void*)(g),
      (__attribute__((address_space(3))) void*)(l), 16, 0, 0);
}

// ---------------- trig table: cos/sin of (1024+s)*theta^(-i/64) ------------
__global__ void build_trig(float* __restrict__ cs, float* __restrict__ sn) {
  int idx = blockIdx.x * 256 + threadIdx.x;   // 65536 = 1024 s * 64 i
  int s = idx >> 6, i = idx & 63;
  float inv = exp2f(-(float)i * (13.287712379549449f / 64.0f)); // 10000^(-i/64)
  float ang = (float)(1024 + s) * inv;
  cs[idx] = cosf(ang);
  sn[idx] = sinf(ang);
}

// ---------------- f32 -> bf16 convert (8/thread) ---------------------------
__global__ void conv_bf16(const float* __restrict__ in, unsigned short* __restrict__ out) {
  size_t i = ((size_t)blockIdx.x * 256 + threadIdx.x) * 8;
  float4 a = *(const float4*)(in + i);
  float4 b = *(const float4*)(in + i + 4);
  u16x8 v;
  v[0] = f2b(a.x); v[1] = f2b(a.y); v[2] = f2b(a.z); v[3] = f2b(a.w);
  v[4] = f2b(b.x); v[5] = f2b(b.y); v[6] = f2b(b.z); v[7] = f2b(b.w);
  *(u16x8*)(out + i) = v;
}

// ---------------- transposed convert: in[R][C] f32 -> out[C][R] bf16 -------
__global__ __launch_bounds__(256) void transpose_conv(
    const float* __restrict__ in, unsigned short* __restrict__ out, int R, int C) {
  __shared__ float tile[32][33];
  int c0 = blockIdx.x * 32, r0 = blockIdx.y * 32;
  int tx = threadIdx.x & 31, ty = threadIdx.x >> 5;   // 32 x 8
#pragma unroll
  for (int j = 0; j < 4; ++j)
    tile[ty + j * 8][tx] = in[(size_t)(r0 + ty + j * 8) * C + c0 + tx];
  __syncthreads();
#pragma unroll
  for (int j = 0; j < 4; ++j)
    out[(size_t)(c0 + ty + j * 8) * R + r0 + tx] = f2b(tile[tx][ty + j * 8]);
}

// ---------------- cache_k f32 -> K_full[:, :1024] bf16 ---------------------
__global__ void copy_k(const float* __restrict__ ck, unsigned short* __restrict__ Kf) {
  size_t idx = ((size_t)blockIdx.x * 256 + threadIdx.x) * 4;  // over 64*1024*128
  size_t bh = idx >> 17, rem = idx & 131071;                  // 1024*128 = 2^17
  float4 a = *(const float4*)(ck + idx);
  u16x4 v;
  v[0] = f2b(a.x); v[1] = f2b(a.y); v[2] = f2b(a.z); v[3] = f2b(a.w);
  *(u16x4*)(Kf + bh * 262144 + rem) = v;                      // 2048*128 row block
}

// ---------------- RoPE q,k from qkv; q scaled by log2e/sqrt(128) -----------
__global__ __launch_bounds__(256) void rope_qk(
    const unsigned short* __restrict__ qkv, const float* __restrict__ cs,
    const float* __restrict__ sn, unsigned short* __restrict__ Qb,
    unsigned short* __restrict__ Kf) {
  int row = blockIdx.x;                 // b*1024 + s
  int b = row >> 10, s = row & 1023;
#pragma unroll
  for (int it = 0; it < 4; ++it) {
    int item = it * 256 + threadIdx.x;  // 16 heads * 64 pairs
    int h = item >> 6, i = item & 63;
    const unsigned short* base = qkv + (size_t)row * 6144 + h * 384;
    float q1 = b2f(base[i]),       q2 = b2f(base[64 + i]);
    float k1 = b2f(base[128 + i]), k2 = b2f(base[192 + i]);
    float c = cs[s * 64 + i], sv = sn[s * 64 + i];
    const float scale = 0.12751738f;    // log2(e)/sqrt(128): softmax in base-2
    size_t bh = (size_t)(b * 16 + h);
    unsigned short* qd = Qb + (bh * 1024 + s) * 128;
    qd[i]      = f2b((q1 * c - q2 * sv) * scale);
    qd[64 + i] = f2b((q2 * c + q1 * sv) * scale);
    unsigned short* kd = Kf + (bh * 2048 + 1024 + s) * 128;
    kd[i]      = f2b(k1 * c - k2 * sv);
    kd[64 + i] = f2b(k2 * c + k1 * sv);
  }
}

// ---------------- V^T build: V_t[b][h][d][s], s<1024 from cache, else qkv --
__global__ __launch_bounds__(256) void build_vt(
    const float* __restrict__ cv, const unsigned short* __restrict__ qkv,
    unsigned short* __restrict__ Vt) {
  __shared__ float tile[32][33];
  int bhid = blockIdx.z;
  int s0 = blockIdx.x * 32, d0 = blockIdx.y * 32;
  int tx = threadIdx.x & 31, ty = threadIdx.x >> 5;
  int b = bhid >> 4, h = bhid & 15;
#pragma unroll
  for (int j = 0; j < 4; ++j) {
    int s = s0 + ty + j * 8, d = d0 + tx;
    float v;
    if (s < 1024) v = cv[((size_t)bhid * 1024 + s) * 128 + d];
    else v = b2f(qkv[((size_t)b * 1024 + (s - 1024)) * 6144 + h * 384 + 256 + d]);
    tile[ty + j * 8][tx] = v;
  }
  __syncthreads();
#pragma unroll
  for (int j = 0; j < 4; ++j) {
    int d = d0 + ty + j * 8, s = s0 + tx;
    Vt[((size_t)bhid * 128 + d) * 2048 + s] = f2b(tile[tx][ty + j * 8]);
  }
}

// ---------------- GEMM: C[M][N] = A[M][K] * B^T  (B given as [N][K]) -------
template <int M, int N, int K, bool OUT_BF16>
__global__ __launch_bounds__(256) void gemm_bt(
    const unsigned short* __restrict__ A, const unsigned short* __restrict__ B,
    void* __restrict__ Cout) {
  __shared__ __align__(16) unsigned short As[128 * 32];
  __shared__ __align__(16) unsigned short Bs[128 * 32];
  constexpr int NT = N / 128;
  int bid = blockIdx.x;
  int tm = bid / NT, tn = bid % NT;
  int tid = threadIdx.x;
  int lane = tid & 63, wave = tid >> 6;
  int wr = (wave >> 1) * 64, wc = (wave & 1) * 64;
  int l15 = lane & 15, g = lane >> 4;

  f32x4 acc[4][4] = {};
  const unsigned short* Ab = A + (size_t)tm * 128 * K;
  const unsigned short* Bb = B + (size_t)tn * 128 * K;

  for (int k0 = 0; k0 < K; k0 += 32) {
#pragma unroll
    for (int is = 0; is < 2; ++is) {
      int p = tid * 16 + is * 4096;          // byte offset in 8KB tile
      int row = p >> 6, kb = p & 63;
      gload_lds16(Ab + (size_t)row * K + k0 + (kb >> 1),
                  (char*)As + is * 4096 + (tid & 192) * 16);
      gload_lds16(Bb + (size_t)row * K + k0 + (kb >> 1),
                  (char*)Bs + is * 4096 + (tid & 192) * 16);
    }
    __syncthreads();
    bf16x8 af[4], bfr[4];
#pragma unroll
    for (int m = 0; m < 4; ++m)
      af[m] = *(const bf16x8*)((const char*)As + (wr + m * 16 + l15) * 64 + g * 16);
#pragma unroll
    for (int n = 0; n < 4; ++n)
      bfr[n] = *(const bf16x8*)((const char*)Bs + (wc + n * 16 + l15) * 64 + g * 16);
#pragma unroll
    for (int m = 0; m < 4; ++m)
#pragma unroll
      for (int n = 0; n < 4; ++n)
        acc[m][n] = __builtin_amdgcn_mfma_f32_16x16x32_bf16(af[m], bfr[n], acc[m][n], 0, 0, 0);
    __syncthreads();
  }
#pragma unroll
  for (int m = 0; m < 4; ++m) {
    int row0 = tm * 128 + wr + m * 16 + g * 4;
#pragma unroll
    for (int n = 0; n < 4; ++n) {
      int col = tn * 128 + wc + n * 16 + l15;
#pragma unroll
      for (int r = 0; r < 4; ++r) {
        size_t off = (size_t)(row0 + r) * N + col;
        if constexpr (OUT_BF16) ((unsigned short*)Cout)[off] = f2b(acc[m][n][r]);
        else ((float*)Cout)[off] = acc[m][n][r];
      }
    }
  }
}

// ---------------- Flash attention ------------------------------------------
// grid = (B*H) * (1024/64); 4 waves, each wave owns 16 q rows (q = lane&15).
// S^T = K*Q^T (base-2 logits); P^T via swizzled LDS; out^T = V^T*P^T.
__global__ __launch_bounds__(256, 4) void attn_kernel(
    const unsigned short* __restrict__ Qb,   // [64][1024][128], pre-scaled
    const unsigned short* __restrict__ Kf,   // [64][2048][128]
    const unsigned short* __restrict__ Vt,   // [64][128][2048]
    unsigned short* __restrict__ Out) {      // [4096][2048] = [b][s][h*128+d]
  __shared__ __align__(16) unsigned short Ks[64 * 128];   // 16KB, XOR-swizzled
  __shared__ __align__(16) unsigned short Vs[128 * 64];   // 16KB, XOR-swizzled
  __shared__ __align__(16) char PsRaw[4 * 2048];          // 8KB  P^T, swizzled
  // total LDS = 40960 -> 4 blocks/CU

  int bid = blockIdx.x;
  bid = (bid & 7) * 128 + (bid >> 3);       // XCD swizzle: 8 heads per XCD
  int bh = bid >> 4, qt = bid & 15;
  int tid = threadIdx.x, lane = tid & 63, wave = tid >> 6;
  int l15 = lane & 15, g = lane >> 4;
  int swz = (l15 & 7) << 4;

  bf16x8 qf[4];
  const unsigned short* qp = Qb + ((size_t)(bh * 1024 + qt * 64 + wave * 16 + l15)) * 128;
#pragma unroll
  for (int kk = 0; kk < 4; ++kk)
    qf[kk] = *(const bf16x8*)(qp + kk * 32 + g * 8);

  // hoisted staging pointers (incremented per kv-tile)
  const unsigned short* Kbase = Kf + (size_t)bh * 2048 * 128;
  const unsigned short* Vbase = Vt + (size_t)bh * 128 * 2048;
  const unsigned short* kptr[4];
  const unsigned short* vptr[4];
  char* kdst[4];
  char* vdst[4];
#pragma unroll
  for (int is = 0; is < 4; ++is) {
    int p = tid * 16 + is * 4096;
    int lgk = p ^ (((p >> 8) & 7) << 4);          // K rows = 256B
    kptr[is] = Kbase + (size_t)(lgk >> 8) * 128 + ((lgk & 255) >> 1);
    kdst[is] = (char*)Ks + is * 4096 + (tid & 192) * 16;
    int lgv = p ^ (((p >> 7) & 7) << 4);          // V^T rows = 128B
    vptr[is] = Vbase + (size_t)(lgv >> 7) * 2048 + ((lgv & 127) >> 1);
    vdst[is] = (char*)Vs + is * 4096 + (tid & 192) * 16;
  }
  char* ps = PsRaw + wave * 2048 + l15 * 128;
  const char* ksA = (const char*)Ks + l15 * 256;  // QK A-frag base (row kv=t*16+l15)
  const char* vsA = (const char*)Vs + l15 * 128;  // PV A-frag base (row d=mt*16+l15)

  float mrun = -1e30f, lsum = 0.f;
  f32x4 acc[8] = {};

  for (int it = 0; it < 32; ++it) {
#pragma unroll
    for (int is = 0; is < 4; ++is) {
      gload_lds16(kptr[is], kdst[is]);  kptr[is] += 64 * 128;
      gload_lds16(vptr[is], vdst[is]);  vptr[is] += 64;
    }
    __syncthreads();

    // S^T tiles: 4 x (16 kv x 16 q), kv = t*16 + g*4 + r per acc reg
    f32x4 st[4] = {};
#pragma unroll
    for (int kk = 0; kk < 4; ++kk) {
#pragma unroll
      for (int t = 0; t < 4; ++t) {
        bf16x8 a = *(const bf16x8*)(ksA + t * 4096 + ((kk * 64 + g * 16) ^ swz));
        st[t] = __builtin_amdgcn_mfma_f32_16x16x32_bf16(a, qf[kk], st[t], 0, 0, 0);
      }
    }

    // online softmax (base-2 domain), max3-friendly tree
    float m0 = fmaxf(fmaxf(st[0][0], st[0][1]), st[0][2]);
    float m1 = fmaxf(fmaxf(st[0][3], st[1][0]), st[1][1]);
    float m2 = fmaxf(fmaxf(st[1][2], st[1][3]), st[2][0]);
    float m3 = fmaxf(fmaxf(st[2][1], st[2][2]), st[2][3]);
    float m4 = fmaxf(fmaxf(st[3][0], st[3][1]), st[3][2]);
    float pmax = fmaxf(fmaxf(fmaxf(m0, m1), fmaxf(m2, m3)), fmaxf(m4, st[3][3]));
    pmax = fmaxf(pmax, __shfl_xor(pmax, 16));
    pmax = fmaxf(pmax, __shfl_xor(pmax, 32));

    if (!__all(pmax - mrun <= 8.0f)) {          // defer-max (T13)
      float mnew = fmaxf(mrun, pmax);
      float corr = exp2f(mrun - mnew);
      lsum *= corr;
#pragma unroll
      for (int mt = 0; mt < 8; ++mt) acc[mt] *= corr;
      mrun = mnew;
    }

    float psA = 0.f, psB = 0.f;
    float pv[4][4];
#pragma unroll
    for (int t = 0; t < 4; ++t) {
      pv[t][0] = exp2f(st[t][0] - mrun);
      pv[t][1] = exp2f(st[t][1] - mrun);
      pv[t][2] = exp2f(st[t][2] - mrun);
      pv[t][3] = exp2f(st[t][3] - mrun);
      psA += pv[t][0] + pv[t][1];
      psB += pv[t][2] + pv[t][3];
    }
    float psum = psA + psB;
    psum += __shfl_xor(psum, 16);
    psum += __shfl_xor(psum, 32);
    lsum += psum;

    // pack P^T to per-wave LDS: row q=l15 (128B, swizzled), col kv
#pragma unroll
    for (int t = 0; t < 4; ++t) {
      uint2 w;
      w.x = cvt_pk_bf16(pv[t][0], pv[t][1]);
      w.y = cvt_pk_bf16(pv[t][2], pv[t][3]);
      *(uint2*)(ps + ((t * 32 + g * 8) ^ swz)) = w;
    }

    // out^T += V^T * P^T
#pragma unroll
    for (int k2 = 0; k2 < 2; ++k2) {
      bf16x8 pfr = *(const bf16x8*)(ps + ((k2 * 64 + g * 16) ^ swz));
#pragma unroll
      for (int mt = 0; mt < 8; ++mt) {
        bf16x8 a = *(const bf16x8*)(vsA + mt * 2048 + ((k2 * 64 + g * 16) ^ swz));
        acc[mt] = __builtin_amdgcn_mfma_f32_16x16x32_bf16(a, pfr, acc[mt], 0, 0, 0);
      }
    }
    __syncthreads();
  }

  float inv = 1.f / lsum;
  int b = bh >> 4, h = bh & 15;
  int sq = qt * 64 + wave * 16 + l15;
  unsigned short* orow = Out + ((size_t)(b * 1024 + sq) * 16 + h) * 128;
#pragma unroll
  for (int mt = 0; mt < 8; ++mt) {
    uint2 w;
    w.x = cvt_pk_bf16(acc[mt][0] * inv, acc[mt][1] * inv);
    w.y = cvt_pk_bf16(acc[mt][2] * inv, acc[mt][3] * inv);
    *(uint2*)(orow + mt * 16 + g * 4) = w;
  }
}

// ---------------------------------------------------------------------------
extern "C" void kernel_launch(void* const* d_in, const int* in_sizes, int n_in,
                              void* d_out, int out_size, void* d_ws, size_t ws_size,
                              hipStream_t stream) {
  const float* x       = (const float*)d_in[0];
  const float* cache_k = (const float*)d_in[1];
  const float* cache_v = (const float*)d_in[2];
  const float* w_qkv   = (const float*)d_in[3];
  const float* w_o     = (const float*)d_in[4];
  float* out = (float*)d_out;

  // workspace layout (~176.5 MiB)
  char* W = (char*)d_ws;
  constexpr size_t O_TRIG = 0;                       // 2 * 256KB
  constexpr size_t O_XB   = 524288;                  // 16MB (reused as attn_out)
  constexpr size_t O_WQT  = O_XB  + 16777216;        // 24MB
  constexpr size_t O_WOT  = O_WQT + 25165824;        // 8MB
  constexpr size_t O_QKV  = O_WOT + 8388608;         // 48MB
  constexpr size_t O_QB   = O_QKV + 50331648;        // 16MB
  constexpr size_t O_KF   = O_QB  + 16777216;        // 32MB
  constexpr size_t O_VT   = O_KF  + 33554432;        // 32MB
  float* cs_tab = (float*)(W + O_TRIG);
  float* sn_tab = (float*)(W + O_TRIG + 262144);
  unsigned short* xb   = (unsigned short*)(W + O_XB);
  unsigned short* wqT  = (unsigned short*)(W + O_WQT);
  unsigned short* woT  = (unsigned short*)(W + O_WOT);
  unsigned short* qkv  = (unsigned short*)(W + O_QKV);
  unsigned short* qb   = (unsigned short*)(W + O_QB);
  unsigned short* Kf   = (unsigned short*)(W + O_KF);
  unsigned short* Vt   = (unsigned short*)(W + O_VT);
  unsigned short* attn_out = xb;   // xb dead after gemm1

  build_trig<<<256, 256, 0, stream>>>(cs_tab, sn_tab);
  conv_bf16<<<4096, 256, 0, stream>>>(x, xb);                       // 8.4M elems
  transpose_conv<<<dim3(192, 64), 256, 0, stream>>>(w_qkv, wqT, 2048, 6144);
  transpose_conv<<<dim3(64, 64), 256, 0, stream>>>(w_o, woT, 2048, 2048);
  gemm_bt<4096, 6144, 2048, true><<<32 * 48, 256, 0, stream>>>(xb, wqT, qkv);
  rope_qk<<<4096, 256, 0, stream>>>(qkv, cs_tab, sn_tab, qb, Kf);
  copy_k<<<8192, 256, 0, stream>>>(cache_k, Kf);
  build_vt<<<dim3(64, 4, 64), 256, 0, stream>>>(cache_v, qkv, Vt);
  attn_kernel<<<1024, 256, 0, stream>>>(qb, Kf, Vt, attn_out);
  gemm_bt<4096, 2048, 2048, false><<<32 * 16, 256, 0, stream>>>(attn_out, woT, out);
}

// Round 3
// 361.273 us; speedup vs baseline: 1.1403x; 1.0393x over previous
//
#include <hip/hip_runtime.h>

// ---------------------------------------------------------------------------
// Attention layer: qkv proj -> RoPE -> concat KV cache -> softmax attn -> out proj
// B=4 Sq=1024 Skv_cache=1024 H=16 D=128 D_MODEL=2048
// bf16 MFMA everywhere. GEMMs: ring-3 counted-vmcnt pipeline (T3+T4+T5).
// Flash attention: swapped QK^T, XOR-swizzled LDS, base-2 softmax, defer-max.
// ---------------------------------------------------------------------------

typedef __bf16 bf16x8 __attribute__((ext_vector_type(8)));
typedef float f32x4 __attribute__((ext_vector_type(4)));
typedef unsigned short u16x8 __attribute__((ext_vector_type(8)));
typedef unsigned short u16x4 __attribute__((ext_vector_type(4)));

__device__ __forceinline__ float b2f(unsigned short u) {
  return __builtin_bit_cast(float, (unsigned int)u << 16);
}
__device__ __forceinline__ unsigned short f2b(float f) {
  unsigned int x = __builtin_bit_cast(unsigned int, f);
  x += 0x7fffu + ((x >> 16) & 1u);   // RNE (finite values only)
  return (unsigned short)(x >> 16);
}
__device__ __forceinline__ unsigned int cvt_pk_bf16(float lo, float hi) {
  unsigned int r;
  asm("v_cvt_pk_bf16_f32 %0, %1, %2" : "=v"(r) : "v"(lo), "v"(hi));
  return r;
}
__device__ __forceinline__ void gload_lds16(const void* g, void* l) {
  __builtin_amdgcn_global_load_lds(
      (__attribute__((address_space(1))) void*)(g),
      (__attribute__((address_space(3))) void*)(l), 16, 0, 0);
}
__device__ __forceinline__ void barrier_nodrain() {
  asm volatile("" ::: "memory");
  __builtin_amdgcn_s_barrier();
  asm volatile("" ::: "memory");
}

// ---------------- trig table: cos/sin of (1024+s)*theta^(-i/64) ------------
__global__ void build_trig(float* __restrict__ cs, float* __restrict__ sn) {
  int idx = blockIdx.x * 256 + threadIdx.x;   // 65536 = 1024 s * 64 i
  int s = idx >> 6, i = idx & 63;
  float inv = exp2f(-(float)i * (13.287712379549449f / 64.0f)); // 10000^(-i/64)
  float ang = (float)(1024 + s) * inv;
  cs[idx] = cosf(ang);
  sn[idx] = sinf(ang);
}

// ---------------- f32 -> bf16 convert (8/thread) ---------------------------
__global__ void conv_bf16(const float* __restrict__ in, unsigned short* __restrict__ out) {
  size_t i = ((size_t)blockIdx.x * 256 + threadIdx.x) * 8;
  float4 a = *(const float4*)(in + i);
  float4 b = *(const float4*)(in + i + 4);
  u16x8 v;
  v[0] = f2b(a.x); v[1] = f2b(a.y); v[2] = f2b(a.z); v[3] = f2b(a.w);
  v[4] = f2b(b.x); v[5] = f2b(b.y); v[6] = f2b(b.z); v[7] = f2b(b.w);
  *(u16x8*)(out + i) = v;
}

// ---------------- transposed convert: in[R][C] f32 -> out[C][R] bf16 -------
__global__ __launch_bounds__(256) void transpose_conv(
    const float* __restrict__ in, unsigned short* __restrict__ out, int R, int C) {
  __shared__ float tile[32][33];
  int c0 = blockIdx.x * 32, r0 = blockIdx.y * 32;
  int tx = threadIdx.x & 31, ty = threadIdx.x >> 5;   // 32 x 8
#pragma unroll
  for (int j = 0; j < 4; ++j)
    tile[ty + j * 8][tx] = in[(size_t)(r0 + ty + j * 8) * C + c0 + tx];
  __syncthreads();
#pragma unroll
  for (int j = 0; j < 4; ++j)
    out[(size_t)(c0 + ty + j * 8) * R + r0 + tx] = f2b(tile[tx][ty + j * 8]);
}

// ---------------- cache_k f32 -> K_full[:, :1024] bf16 ---------------------
__global__ void copy_k(const float* __restrict__ ck, unsigned short* __restrict__ Kf) {
  size_t idx = ((size_t)blockIdx.x * 256 + threadIdx.x) * 4;  // over 64*1024*128
  size_t bh = idx >> 17, rem = idx & 131071;                  // 1024*128 = 2^17
  float4 a = *(const float4*)(ck + idx);
  u16x4 v;
  v[0] = f2b(a.x); v[1] = f2b(a.y); v[2] = f2b(a.z); v[3] = f2b(a.w);
  *(u16x4*)(Kf + bh * 262144 + rem) = v;                      // 2048*128 row block
}

// ---------------- RoPE q,k from qkv; q scaled by log2e/sqrt(128) -----------
__global__ __launch_bounds__(256) void rope_qk(
    const unsigned short* __restrict__ qkv, const float* __restrict__ cs,
    const float* __restrict__ sn, unsigned short* __restrict__ Qb,
    unsigned short* __restrict__ Kf) {
  int row = blockIdx.x;                 // b*1024 + s
  int b = row >> 10, s = row & 1023;
#pragma unroll
  for (int it = 0; it < 4; ++it) {
    int item = it * 256 + threadIdx.x;  // 16 heads * 64 pairs
    int h = item >> 6, i = item & 63;
    const unsigned short* base = qkv + (size_t)row * 6144 + h * 384;
    float q1 = b2f(base[i]),       q2 = b2f(base[64 + i]);
    float k1 = b2f(base[128 + i]), k2 = b2f(base[192 + i]);
    float c = cs[s * 64 + i], sv = sn[s * 64 + i];
    const float scale = 0.12751738f;    // log2(e)/sqrt(128): softmax in base-2
    size_t bh = (size_t)(b * 16 + h);
    unsigned short* qd = Qb + (bh * 1024 + s) * 128;
    qd[i]      = f2b((q1 * c - q2 * sv) * scale);
    qd[64 + i] = f2b((q2 * c + q1 * sv) * scale);
    unsigned short* kd = Kf + (bh * 2048 + 1024 + s) * 128;
    kd[i]      = f2b(k1 * c - k2 * sv);
    kd[64 + i] = f2b(k2 * c + k1 * sv);
  }
}

// ---------------- V^T build: V_t[b][h][d][s], s<1024 from cache, else qkv --
__global__ __launch_bounds__(256) void build_vt(
    const float* __restrict__ cv, const unsigned short* __restrict__ qkv,
    unsigned short* __restrict__ Vt) {
  __shared__ float tile[32][33];
  int bhid = blockIdx.z;
  int s0 = blockIdx.x * 32, d0 = blockIdx.y * 32;
  int tx = threadIdx.x & 31, ty = threadIdx.x >> 5;
  int b = bhid >> 4, h = bhid & 15;
#pragma unroll
  for (int j = 0; j < 4; ++j) {
    int s = s0 + ty + j * 8, d = d0 + tx;
    float v;
    if (s < 1024) v = cv[((size_t)bhid * 1024 + s) * 128 + d];
    else v = b2f(qkv[((size_t)b * 1024 + (s - 1024)) * 6144 + h * 384 + 256 + d]);
    tile[ty + j * 8][tx] = v;
  }
  __syncthreads();
#pragma unroll
  for (int j = 0; j < 4; ++j) {
    int d = d0 + ty + j * 8, s = s0 + tx;
    Vt[((size_t)bhid * 128 + d) * 2048 + s] = f2b(tile[tx][ty + j * 8]);
  }
}

// ---------------- GEMM: C[M][N] = A[M][K] * B^T  (B given as [N][K]) -------
// Ring-3 counted-vmcnt pipeline. BM=256 BN=128 BK=32, 8 waves (4M x 2N),
// per-wave 64x64 (4x4 16x16x32 frags). LDS: 3 slots x (A 16KB + B 8KB) = 72KB
// -> 2 blocks/CU. Ledger: at tile t, outstanding = {t+1,t+2} = 6 loads;
// vmcnt(3) completes tile t+1; next barrier certifies it block-wide. Slot
// (t+2)%3 was last read at tile t-1 (reads done before this barrier).
template <int M, int N, int K, bool OUT_BF16>
__global__ __launch_bounds__(512, 4) void gemm_ring(
    const unsigned short* __restrict__ A, const unsigned short* __restrict__ B,
    void* __restrict__ Cout) {
  __shared__ __align__(16) char lds[3 * 24576];
  constexpr int NT = N / 128;
  constexpr int Kt = K / 32;
  int bid = blockIdx.x;
  int tm = bid / NT, tn = bid % NT;
  int tid = threadIdx.x;
  int lane = tid & 63, wave = tid >> 6;
  int wr = (wave >> 1) * 64, wc = (wave & 1) * 64;
  int l15 = lane & 15, g = lane >> 4;

  int p = tid * 16;   // byte position in a 16KB/8KB staging region
  const unsigned short* aSrc0 = A + (size_t)(tm * 256 + (p >> 6)) * K + ((p & 63) >> 1);
  const unsigned short* aSrc1 = aSrc0 + (size_t)128 * K;   // rows 128..255
  const unsigned short* bSrc  = B + (size_t)(tn * 128 + (p >> 6)) * K + ((p & 63) >> 1);

  f32x4 acc[4][4] = {};

  auto stage = [&](int s) {
    char* base = (char*)lds + s * 24576;
    gload_lds16(aSrc0, base + p);
    gload_lds16(aSrc1, base + 8192 + p);
    gload_lds16(bSrc,  base + 16384 + p);
    aSrc0 += 32; aSrc1 += 32; bSrc += 32;
  };

  stage(0);
  stage(1);
  asm volatile("s_waitcnt vmcnt(3)" ::: "memory");   // tile 0 complete (mine)

  int slot = 0, sNext = 2;
  for (int t = 0; t < Kt; ++t) {
    barrier_nodrain();                 // certifies tile t staged block-wide
    if (t + 2 < Kt) {
      stage(sNext);
      sNext = (sNext == 2) ? 0 : sNext + 1;
      asm volatile("s_waitcnt vmcnt(3)" ::: "memory");   // tile t+1 complete (mine)
    } else {
      asm volatile("s_waitcnt vmcnt(0)" ::: "memory");   // tail drain
    }
    const char* As_ = (const char*)lds + slot * 24576;
    const char* Bs_ = As_ + 16384;
    bf16x8 af[4], bfr[4];
#pragma unroll
    for (int m = 0; m < 4; ++m)
      af[m] = *(const bf16x8*)(As_ + (wr + m * 16 + l15) * 64 + g * 16);
#pragma unroll
    for (int n = 0; n < 4; ++n)
      bfr[n] = *(const bf16x8*)(Bs_ + (wc + n * 16 + l15) * 64 + g * 16);
    __builtin_amdgcn_s_setprio(1);
#pragma unroll
    for (int m = 0; m < 4; ++m)
#pragma unroll
      for (int n = 0; n < 4; ++n)
        acc[m][n] = __builtin_amdgcn_mfma_f32_16x16x32_bf16(af[m], bfr[n], acc[m][n], 0, 0, 0);
    __builtin_amdgcn_s_setprio(0);
    slot = (slot == 2) ? 0 : slot + 1;
  }

#pragma unroll
  for (int m = 0; m < 4; ++m) {
    int row0 = tm * 256 + wr + m * 16 + g * 4;
#pragma unroll
    for (int n = 0; n < 4; ++n) {
      int col = tn * 128 + wc + n * 16 + l15;
#pragma unroll
      for (int r = 0; r < 4; ++r) {
        size_t off = (size_t)(row0 + r) * N + col;
        if constexpr (OUT_BF16) ((unsigned short*)Cout)[off] = f2b(acc[m][n][r]);
        else ((float*)Cout)[off] = acc[m][n][r];
      }
    }
  }
}

// ---------------- Flash attention ------------------------------------------
// grid = (B*H) * (1024/64); 4 waves, each wave owns 16 q rows (q = lane&15).
// S^T = K*Q^T (base-2 logits); P^T via swizzled LDS; out^T = V^T*P^T.
__global__ __launch_bounds__(256, 4) void attn_kernel(
    const unsigned short* __restrict__ Qb,   // [64][1024][128], pre-scaled
    const unsigned short* __restrict__ Kf,   // [64][2048][128]
    const unsigned short* __restrict__ Vt,   // [64][128][2048]
    unsigned short* __restrict__ Out) {      // [4096][2048] = [b][s][h*128+d]
  __shared__ __align__(16) unsigned short Ks[64 * 128];   // 16KB, XOR-swizzled
  __shared__ __align__(16) unsigned short Vs[128 * 64];   // 16KB, XOR-swizzled
  __shared__ __align__(16) char PsRaw[4 * 2048];          // 8KB  P^T, swizzled
  // total LDS = 40960 -> 4 blocks/CU

  int bid = blockIdx.x;
  bid = (bid & 7) * 128 + (bid >> 3);       // XCD swizzle: 8 heads per XCD
  int bh = bid >> 4, qt = bid & 15;
  int tid = threadIdx.x, lane = tid & 63, wave = tid >> 6;
  int l15 = lane & 15, g = lane >> 4;
  int swz = (l15 & 7) << 4;

  bf16x8 qf[4];
  const unsigned short* qp = Qb + ((size_t)(bh * 1024 + qt * 64 + wave * 16 + l15)) * 128;
#pragma unroll
  for (int kk = 0; kk < 4; ++kk)
    qf[kk] = *(const bf16x8*)(qp + kk * 32 + g * 8);

  // hoisted staging pointers (incremented per kv-tile)
  const unsigned short* Kbase = Kf + (size_t)bh * 2048 * 128;
  const unsigned short* Vbase = Vt + (size_t)bh * 128 * 2048;
  const unsigned short* kptr[4];
  const unsigned short* vptr[4];
  char* kdst[4];
  char* vdst[4];
#pragma unroll
  for (int is = 0; is < 4; ++is) {
    int p = tid * 16 + is * 4096;
    int lgk = p ^ (((p >> 8) & 7) << 4);          // K rows = 256B
    kptr[is] = Kbase + (size_t)(lgk >> 8) * 128 + ((lgk & 255) >> 1);
    kdst[is] = (char*)Ks + is * 4096 + (tid & 192) * 16;
    int lgv = p ^ (((p >> 7) & 7) << 4);          // V^T rows = 128B
    vptr[is] = Vbase + (size_t)(lgv >> 7) * 2048 + ((lgv & 127) >> 1);
    vdst[is] = (char*)Vs + is * 4096 + (tid & 192) * 16;
  }
  char* ps = PsRaw + wave * 2048 + l15 * 128;
  const char* ksA = (const char*)Ks + l15 * 256;  // QK A-frag base (row kv=t*16+l15)
  const char* vsA = (const char*)Vs + l15 * 128;  // PV A-frag base (row d=mt*16+l15)

  float mrun = -1e30f, lsum = 0.f;
  f32x4 acc[8] = {};

  for (int it = 0; it < 32; ++it) {
#pragma unroll
    for (int is = 0; is < 4; ++is) {
      gload_lds16(kptr[is], kdst[is]);  kptr[is] += 64 * 128;
      gload_lds16(vptr[is], vdst[is]);  vptr[is] += 64;
    }
    __syncthreads();

    // S^T tiles: 4 x (16 kv x 16 q), kv = t*16 + g*4 + r per acc reg
    f32x4 st[4] = {};
#pragma unroll
    for (int kk = 0; kk < 4; ++kk) {
#pragma unroll
      for (int t = 0; t < 4; ++t) {
        bf16x8 a = *(const bf16x8*)(ksA + t * 4096 + ((kk * 64 + g * 16) ^ swz));
        st[t] = __builtin_amdgcn_mfma_f32_16x16x32_bf16(a, qf[kk], st[t], 0, 0, 0);
      }
    }

    // online softmax (base-2 domain), max3-friendly tree
    float m0 = fmaxf(fmaxf(st[0][0], st[0][1]), st[0][2]);
    float m1 = fmaxf(fmaxf(st[0][3], st[1][0]), st[1][1]);
    float m2 = fmaxf(fmaxf(st[1][2], st[1][3]), st[2][0]);
    float m3 = fmaxf(fmaxf(st[2][1], st[2][2]), st[2][3]);
    float m4 = fmaxf(fmaxf(st[3][0], st[3][1]), st[3][2]);
    float pmax = fmaxf(fmaxf(fmaxf(m0, m1), fmaxf(m2, m3)), fmaxf(m4, st[3][3]));
    pmax = fmaxf(pmax, __shfl_xor(pmax, 16));
    pmax = fmaxf(pmax, __shfl_xor(pmax, 32));

    if (!__all(pmax - mrun <= 8.0f)) {          // defer-max (T13)
      float mnew = fmaxf(mrun, pmax);
      float corr = exp2f(mrun - mnew);
      lsum *= corr;
#pragma unroll
      for (int mt = 0; mt < 8; ++mt) acc[mt] *= corr;
      mrun = mnew;
    }

    float psA = 0.f, psB = 0.f;
    float pv[4][4];
#pragma unroll
    for (int t = 0; t < 4; ++t) {
      pv[t][0] = exp2f(st[t][0] - mrun);
      pv[t][1] = exp2f(st[t][1] - mrun);
      pv[t][2] = exp2f(st[t][2] - mrun);
      pv[t][3] = exp2f(st[t][3] - mrun);
      psA += pv[t][0] + pv[t][1];
      psB += pv[t][2] + pv[t][3];
    }
    float psum = psA + psB;
    psum += __shfl_xor(psum, 16);
    psum += __shfl_xor(psum, 32);
    lsum += psum;

    // pack P^T to per-wave LDS: row q=l15 (128B, swizzled), col kv
#pragma unroll
    for (int t = 0; t < 4; ++t) {
      uint2 w;
      w.x = cvt_pk_bf16(pv[t][0], pv[t][1]);
      w.y = cvt_pk_bf16(pv[t][2], pv[t][3]);
      *(uint2*)(ps + ((t * 32 + g * 8) ^ swz)) = w;
    }

    // out^T += V^T * P^T
#pragma unroll
    for (int k2 = 0; k2 < 2; ++k2) {
      bf16x8 pfr = *(const bf16x8*)(ps + ((k2 * 64 + g * 16) ^ swz));
#pragma unroll
      for (int mt = 0; mt < 8; ++mt) {
        bf16x8 a = *(const bf16x8*)(vsA + mt * 2048 + ((k2 * 64 + g * 16) ^ swz));
        acc[mt] = __builtin_amdgcn_mfma_f32_16x16x32_bf16(a, pfr, acc[mt], 0, 0, 0);
      }
    }
    __syncthreads();
  }

  float inv = 1.f / lsum;
  int b = bh >> 4, h = bh & 15;
  int sq = qt * 64 + wave * 16 + l15;
  unsigned short* orow = Out + ((size_t)(b * 1024 + sq) * 16 + h) * 128;
#pragma unroll
  for (int mt = 0; mt < 8; ++mt) {
    uint2 w;
    w.x = cvt_pk_bf16(acc[mt][0] * inv, acc[mt][1] * inv);
    w.y = cvt_pk_bf16(acc[mt][2] * inv, acc[mt][3] * inv);
    *(uint2*)(orow + mt * 16 + g * 4) = w;
  }
}

// ---------------------------------------------------------------------------
extern "C" void kernel_launch(void* const* d_in, const int* in_sizes, int n_in,
                              void* d_out, int out_size, void* d_ws, size_t ws_size,
                              hipStream_t stream) {
  const float* x       = (const float*)d_in[0];
  const float* cache_k = (const float*)d_in[1];
  const float* cache_v = (const float*)d_in[2];
  const float* w_qkv   = (const float*)d_in[3];
  const float* w_o     = (const float*)d_in[4];
  float* out = (float*)d_out;

  // workspace layout (~176.5 MiB)
  char* W = (char*)d_ws;
  constexpr size_t O_TRIG = 0;                       // 2 * 256KB
  constexpr size_t O_XB   = 524288;                  // 16MB (reused as attn_out)
  constexpr size_t O_WQT  = O_XB  + 16777216;        // 24MB
  constexpr size_t O_WOT  = O_WQT + 25165824;        // 8MB
  constexpr size_t O_QKV  = O_WOT + 8388608;         // 48MB
  constexpr size_t O_QB   = O_QKV + 50331648;        // 16MB
  constexpr size_t O_KF   = O_QB  + 16777216;        // 32MB
  constexpr size_t O_VT   = O_KF  + 33554432;        // 32MB
  float* cs_tab = (float*)(W + O_TRIG);
  float* sn_tab = (float*)(W + O_TRIG + 262144);
  unsigned short* xb   = (unsigned short*)(W + O_XB);
  unsigned short* wqT  = (unsigned short*)(W + O_WQT);
  unsigned short* woT  = (unsigned short*)(W + O_WOT);
  unsigned short* qkv  = (unsigned short*)(W + O_QKV);
  unsigned short* qb   = (unsigned short*)(W + O_QB);
  unsigned short* Kf   = (unsigned short*)(W + O_KF);
  unsigned short* Vt   = (unsigned short*)(W + O_VT);
  unsigned short* attn_out = xb;   // xb dead after gemm1

  build_trig<<<256, 256, 0, stream>>>(cs_tab, sn_tab);
  conv_bf16<<<4096, 256, 0, stream>>>(x, xb);                       // 8.4M elems
  transpose_conv<<<dim3(192, 64), 256, 0, stream>>>(w_qkv, wqT, 2048, 6144);
  transpose_conv<<<dim3(64, 64), 256, 0, stream>>>(w_o, woT, 2048, 2048);
  gemm_ring<4096, 6144, 2048, true><<<768, 512, 0, stream>>>(xb, wqT, qkv);
  rope_qk<<<4096, 256, 0, stream>>>(qkv, cs_tab, sn_tab, qb, Kf);
  copy_k<<<8192, 256, 0, stream>>>(cache_k, Kf);
  build_vt<<<dim3(64, 4, 64), 256, 0, stream>>>(cache_v, qkv, Vt);
  attn_kernel<<<1024, 256, 0, stream>>>(qb, Kf, Vt, attn_out);
  gemm_ring<4096, 2048, 2048, false><<<256, 512, 0, stream>>>(attn_out, woT, out);
}

// Round 4
// 359.257 us; speedup vs baseline: 1.1467x; 1.0056x over previous
//
#include <hip/hip_runtime.h>

// ---------------------------------------------------------------------------
// Attention layer: qkv proj -> RoPE -> concat KV cache -> softmax attn -> out proj
// B=4 Sq=1024 Skv_cache=1024 H=16 D=128 D_MODEL=2048
// bf16 MFMA everywhere. GEMMs: ring-3 counted-vmcnt pipeline (T3+T4+T5).
// Flash attention: double-buffered K/V (counted vmcnt(8)), swapped QK^T,
// XOR-swizzled LDS, base-2 softmax, defer-max, lsum via ones-MFMA.
// ---------------------------------------------------------------------------

typedef __bf16 bf16x8 __attribute__((ext_vector_type(8)));
typedef float f32x4 __attribute__((ext_vector_type(4)));
typedef unsigned short u16x8 __attribute__((ext_vector_type(8)));
typedef unsigned short u16x4 __attribute__((ext_vector_type(4)));

__device__ __forceinline__ float b2f(unsigned short u) {
  return __builtin_bit_cast(float, (unsigned int)u << 16);
}
__device__ __forceinline__ unsigned short f2b(float f) {
  unsigned int x = __builtin_bit_cast(unsigned int, f);
  x += 0x7fffu + ((x >> 16) & 1u);   // RNE (finite values only)
  return (unsigned short)(x >> 16);
}
__device__ __forceinline__ unsigned int cvt_pk_bf16(float lo, float hi) {
  unsigned int r;
  asm("v_cvt_pk_bf16_f32 %0, %1, %2" : "=v"(r) : "v"(lo), "v"(hi));
  return r;
}
__device__ __forceinline__ void gload_lds16(const void* g, void* l) {
  __builtin_amdgcn_global_load_lds(
      (__attribute__((address_space(1))) void*)(g),
      (__attribute__((address_space(3))) void*)(l), 16, 0, 0);
}
__device__ __forceinline__ void barrier_nodrain() {
  asm volatile("" ::: "memory");
  __builtin_amdgcn_s_barrier();
  asm volatile("" ::: "memory");
}

// ---------------- trig table: cos/sin of (1024+s)*theta^(-i/64) ------------
__global__ void build_trig(float* __restrict__ cs, float* __restrict__ sn) {
  int idx = blockIdx.x * 256 + threadIdx.x;   // 65536 = 1024 s * 64 i
  int s = idx >> 6, i = idx & 63;
  float inv = exp2f(-(float)i * (13.287712379549449f / 64.0f)); // 10000^(-i/64)
  float ang = (float)(1024 + s) * inv;
  cs[idx] = cosf(ang);
  sn[idx] = sinf(ang);
}

// ---------------- f32 -> bf16 convert (8/thread) ---------------------------
__global__ void conv_bf16(const float* __restrict__ in, unsigned short* __restrict__ out) {
  size_t i = ((size_t)blockIdx.x * 256 + threadIdx.x) * 8;
  float4 a = *(const float4*)(in + i);
  float4 b = *(const float4*)(in + i + 4);
  u16x8 v;
  v[0] = f2b(a.x); v[1] = f2b(a.y); v[2] = f2b(a.z); v[3] = f2b(a.w);
  v[4] = f2b(b.x); v[5] = f2b(b.y); v[6] = f2b(b.z); v[7] = f2b(b.w);
  *(u16x8*)(out + i) = v;
}

// ---------------- transposed convert: in[R][C] f32 -> out[C][R] bf16 -------
__global__ __launch_bounds__(256) void transpose_conv(
    const float* __restrict__ in, unsigned short* __restrict__ out, int R, int C) {
  __shared__ float tile[32][33];
  int c0 = blockIdx.x * 32, r0 = blockIdx.y * 32;
  int tx = threadIdx.x & 31, ty = threadIdx.x >> 5;   // 32 x 8
#pragma unroll
  for (int j = 0; j < 4; ++j)
    tile[ty + j * 8][tx] = in[(size_t)(r0 + ty + j * 8) * C + c0 + tx];
  __syncthreads();
#pragma unroll
  for (int j = 0; j < 4; ++j)
    out[(size_t)(c0 + ty + j * 8) * R + r0 + tx] = f2b(tile[tx][ty + j * 8]);
}

// ---------------- cache_k f32 -> K_full[:, :1024] bf16 ---------------------
__global__ void copy_k(const float* __restrict__ ck, unsigned short* __restrict__ Kf) {
  size_t idx = ((size_t)blockIdx.x * 256 + threadIdx.x) * 4;  // over 64*1024*128
  size_t bh = idx >> 17, rem = idx & 131071;                  // 1024*128 = 2^17
  float4 a = *(const float4*)(ck + idx);
  u16x4 v;
  v[0] = f2b(a.x); v[1] = f2b(a.y); v[2] = f2b(a.z); v[3] = f2b(a.w);
  *(u16x4*)(Kf + bh * 262144 + rem) = v;                      // 2048*128 row block
}

// ---------------- RoPE q,k from qkv; q scaled by log2e/sqrt(128) -----------
__global__ __launch_bounds__(256) void rope_qk(
    const unsigned short* __restrict__ qkv, const float* __restrict__ cs,
    const float* __restrict__ sn, unsigned short* __restrict__ Qb,
    unsigned short* __restrict__ Kf) {
  int row = blockIdx.x;                 // b*1024 + s
  int b = row >> 10, s = row & 1023;
#pragma unroll
  for (int it = 0; it < 4; ++it) {
    int item = it * 256 + threadIdx.x;  // 16 heads * 64 pairs
    int h = item >> 6, i = item & 63;
    const unsigned short* base = qkv + (size_t)row * 6144 + h * 384;
    float q1 = b2f(base[i]),       q2 = b2f(base[64 + i]);
    float k1 = b2f(base[128 + i]), k2 = b2f(base[192 + i]);
    float c = cs[s * 64 + i], sv = sn[s * 64 + i];
    const float scale = 0.12751738f;    // log2(e)/sqrt(128): softmax in base-2
    size_t bh = (size_t)(b * 16 + h);
    unsigned short* qd = Qb + (bh * 1024 + s) * 128;
    qd[i]      = f2b((q1 * c - q2 * sv) * scale);
    qd[64 + i] = f2b((q2 * c + q1 * sv) * scale);
    unsigned short* kd = Kf + (bh * 2048 + 1024 + s) * 128;
    kd[i]      = f2b(k1 * c - k2 * sv);
    kd[64 + i] = f2b(k2 * c + k1 * sv);
  }
}

// ---------------- V^T build: V_t[b][h][d][s], s<1024 from cache, else qkv --
__global__ __launch_bounds__(256) void build_vt(
    const float* __restrict__ cv, const unsigned short* __restrict__ qkv,
    unsigned short* __restrict__ Vt) {
  __shared__ float tile[32][33];
  int bhid = blockIdx.z;
  int s0 = blockIdx.x * 32, d0 = blockIdx.y * 32;
  int tx = threadIdx.x & 31, ty = threadIdx.x >> 5;
  int b = bhid >> 4, h = bhid & 15;
#pragma unroll
  for (int j = 0; j < 4; ++j) {
    int s = s0 + ty + j * 8, d = d0 + tx;
    float v;
    if (s < 1024) v = cv[((size_t)bhid * 1024 + s) * 128 + d];
    else v = b2f(qkv[((size_t)b * 1024 + (s - 1024)) * 6144 + h * 384 + 256 + d]);
    tile[ty + j * 8][tx] = v;
  }
  __syncthreads();
#pragma unroll
  for (int j = 0; j < 4; ++j) {
    int d = d0 + ty + j * 8, s = s0 + tx;
    Vt[((size_t)bhid * 128 + d) * 2048 + s] = f2b(tile[tx][ty + j * 8]);
  }
}

// ---------------- GEMM: C[M][N] = A[M][K] * B^T  (B given as [N][K]) -------
// Ring-3 counted-vmcnt pipeline. BM=256 BN=128 BK=32, 8 waves (4M x 2N),
// per-wave 64x64 (4x4 16x16x32 frags). LDS: 3 slots x (A 16KB + B 8KB) = 72KB
// -> 2 blocks/CU. Ledger: at tile t, outstanding = {t+1,t+2} = 6 loads;
// vmcnt(3) completes tile t+1; next barrier certifies it block-wide. Slot
// (t+2)%3 was last read at tile t-1 (reads done before this barrier).
template <int M, int N, int K, bool OUT_BF16>
__global__ __launch_bounds__(512, 4) void gemm_ring(
    const unsigned short* __restrict__ A, const unsigned short* __restrict__ B,
    void* __restrict__ Cout) {
  __shared__ __align__(16) char lds[3 * 24576];
  constexpr int NT = N / 128;
  constexpr int Kt = K / 32;
  int bid = blockIdx.x;
  int tm = bid / NT, tn = bid % NT;
  int tid = threadIdx.x;
  int lane = tid & 63, wave = tid >> 6;
  int wr = (wave >> 1) * 64, wc = (wave & 1) * 64;
  int l15 = lane & 15, g = lane >> 4;

  int p = tid * 16;   // byte position in a 16KB/8KB staging region
  const unsigned short* aSrc0 = A + (size_t)(tm * 256 + (p >> 6)) * K + ((p & 63) >> 1);
  const unsigned short* aSrc1 = aSrc0 + (size_t)128 * K;   // rows 128..255
  const unsigned short* bSrc  = B + (size_t)(tn * 128 + (p >> 6)) * K + ((p & 63) >> 1);

  f32x4 acc[4][4] = {};

  auto stage = [&](int s) {
    char* base = (char*)lds + s * 24576;
    gload_lds16(aSrc0, base + p);
    gload_lds16(aSrc1, base + 8192 + p);
    gload_lds16(bSrc,  base + 16384 + p);
    aSrc0 += 32; aSrc1 += 32; bSrc += 32;
  };

  stage(0);
  stage(1);
  asm volatile("s_waitcnt vmcnt(3)" ::: "memory");   // tile 0 complete (mine)

  int slot = 0, sNext = 2;
  for (int t = 0; t < Kt; ++t) {
    barrier_nodrain();                 // certifies tile t staged block-wide
    if (t + 2 < Kt) {
      stage(sNext);
      sNext = (sNext == 2) ? 0 : sNext + 1;
      asm volatile("s_waitcnt vmcnt(3)" ::: "memory");   // tile t+1 complete (mine)
    } else {
      asm volatile("s_waitcnt vmcnt(0)" ::: "memory");   // tail drain
    }
    const char* As_ = (const char*)lds + slot * 24576;
    const char* Bs_ = As_ + 16384;
    bf16x8 af[4], bfr[4];
#pragma unroll
    for (int m = 0; m < 4; ++m)
      af[m] = *(const bf16x8*)(As_ + (wr + m * 16 + l15) * 64 + g * 16);
#pragma unroll
    for (int n = 0; n < 4; ++n)
      bfr[n] = *(const bf16x8*)(Bs_ + (wc + n * 16 + l15) * 64 + g * 16);
    __builtin_amdgcn_s_setprio(1);
#pragma unroll
    for (int m = 0; m < 4; ++m)
#pragma unroll
      for (int n = 0; n < 4; ++n)
        acc[m][n] = __builtin_amdgcn_mfma_f32_16x16x32_bf16(af[m], bfr[n], acc[m][n], 0, 0, 0);
    __builtin_amdgcn_s_setprio(0);
    slot = (slot == 2) ? 0 : slot + 1;
  }

#pragma unroll
  for (int m = 0; m < 4; ++m) {
    int row0 = tm * 256 + wr + m * 16 + g * 4;
#pragma unroll
    for (int n = 0; n < 4; ++n) {
      int col = tn * 128 + wc + n * 16 + l15;
#pragma unroll
      for (int r = 0; r < 4; ++r) {
        size_t off = (size_t)(row0 + r) * N + col;
        if constexpr (OUT_BF16) ((unsigned short*)Cout)[off] = f2b(acc[m][n][r]);
        else ((float*)Cout)[off] = acc[m][n][r];
      }
    }
  }
}

// ---------------- Flash attention ------------------------------------------
// grid = (B*H) * (1024/64); 4 waves, each wave owns 16 q rows (q = lane&15).
// Double-buffered K/V, counted vmcnt(8): stage(t+1) issued one iter ahead.
// Ledger: prologue stages tile0 (8 loads). Iter t: barrier (prev compute done
// -> buf[(t+1)&1] free), stage(t+1) -> 16 outstanding, vmcnt(8) -> tile t
// arrived, barrier -> tile t visible block-wide, compute(t). Tail: vmcnt(0).
__global__ __launch_bounds__(256, 2) void attn_kernel(
    const unsigned short* __restrict__ Qb,   // [64][1024][128], pre-scaled
    const unsigned short* __restrict__ Kf,   // [64][2048][128]
    const unsigned short* __restrict__ Vt,   // [64][128][2048]
    unsigned short* __restrict__ Out) {      // [4096][2048] = [b][s][h*128+d]
  __shared__ __align__(16) unsigned short Ks[2][64 * 128];  // 2x16KB, swizzled
  __shared__ __align__(16) unsigned short Vs[2][64 * 128];  // 2x16KB, swizzled
  __shared__ __align__(16) char PsRaw[4 * 2048];            // 8KB per-wave P^T
  // total LDS = 73728 -> 2 blocks/CU

  int bid = blockIdx.x;
  bid = (bid & 7) * 128 + (bid >> 3);       // XCD swizzle: 8 heads per XCD
  int bh = bid >> 4, qt = bid & 15;
  int tid = threadIdx.x, lane = tid & 63, wave = tid >> 6;
  int l15 = lane & 15, g = lane >> 4;
  int swz = (l15 & 7) << 4;

  bf16x8 qf[4];
  const unsigned short* qp = Qb + ((size_t)(bh * 1024 + qt * 64 + wave * 16 + l15)) * 128;
#pragma unroll
  for (int kk = 0; kk < 4; ++kk)
    qf[kk] = *(const bf16x8*)(qp + kk * 32 + g * 8);

  u16x8 ou;
#pragma unroll
  for (int j = 0; j < 8; ++j) ou[j] = 0x3F80;           // bf16 1.0
  bf16x8 ones = __builtin_bit_cast(bf16x8, ou);

  // hoisted staging pointers (incremented per kv-tile)
  const unsigned short* Kbase = Kf + (size_t)bh * 2048 * 128;
  const unsigned short* Vbase = Vt + (size_t)bh * 128 * 2048;
  const unsigned short* kptr[4];
  const unsigned short* vptr[4];
  char* kdst0[4];
  char* vdst0[4];
#pragma unroll
  for (int is = 0; is < 4; ++is) {
    int p = tid * 16 + is * 4096;
    int lgk = p ^ (((p >> 8) & 7) << 4);          // K rows = 256B
    kptr[is] = Kbase + (size_t)(lgk >> 8) * 128 + ((lgk & 255) >> 1);
    kdst0[is] = (char*)Ks + is * 4096 + (tid & 192) * 16;
    int lgv = p ^ (((p >> 7) & 7) << 4);          // V^T rows = 128B
    vptr[is] = Vbase + (size_t)(lgv >> 7) * 2048 + ((lgv & 127) >> 1);
    vdst0[is] = (char*)Vs + is * 4096 + (tid & 192) * 16;
  }
  char* ps = PsRaw + wave * 2048 + l15 * 128;

  auto stage = [&](int buf) {
#pragma unroll
    for (int is = 0; is < 4; ++is) {
      gload_lds16(kptr[is], kdst0[is] + buf * 16384);  kptr[is] += 64 * 128;
      gload_lds16(vptr[is], vdst0[is] + buf * 16384);  vptr[is] += 64;
    }
  };

  float mrun = -1e30f;
  f32x4 acc[8] = {};
  f32x4 acc_l = {};

  stage(0);
  for (int it = 0; it < 32; ++it) {
    int cur = it & 1;
    barrier_nodrain();          // prev compute done -> buf cur^1 reads retired
    if (it + 1 < 32) {
      stage(cur ^ 1);
      asm volatile("s_waitcnt vmcnt(8)" ::: "memory");  // tile it arrived (mine)
    } else {
      asm volatile("s_waitcnt vmcnt(0)" ::: "memory");  // tail drain
    }
    barrier_nodrain();          // tile it visible block-wide
    const char* ksA = (const char*)Ks + cur * 16384 + l15 * 256;
    const char* vsA = (const char*)Vs + cur * 16384 + l15 * 128;

    // S^T tiles: 4 x (16 kv x 16 q), kv = t*16 + g*4 + r per acc reg
    f32x4 st[4] = {};
#pragma unroll
    for (int kk = 0; kk < 4; ++kk) {
#pragma unroll
      for (int t = 0; t < 4; ++t) {
        bf16x8 a = *(const bf16x8*)(ksA + t * 4096 + ((kk * 64 + g * 16) ^ swz));
        st[t] = __builtin_amdgcn_mfma_f32_16x16x32_bf16(a, qf[kk], st[t], 0, 0, 0);
      }
    }

    // online softmax (base-2 domain)
    float m0 = fmaxf(fmaxf(st[0][0], st[0][1]), st[0][2]);
    float m1 = fmaxf(fmaxf(st[0][3], st[1][0]), st[1][1]);
    float m2 = fmaxf(fmaxf(st[1][2], st[1][3]), st[2][0]);
    float m3 = fmaxf(fmaxf(st[2][1], st[2][2]), st[2][3]);
    float m4 = fmaxf(fmaxf(st[3][0], st[3][1]), st[3][2]);
    float pmax = fmaxf(fmaxf(fmaxf(m0, m1), fmaxf(m2, m3)), fmaxf(m4, st[3][3]));
    pmax = fmaxf(pmax, __shfl_xor(pmax, 16));
    pmax = fmaxf(pmax, __shfl_xor(pmax, 32));

    if (!__all(pmax - mrun <= 8.0f)) {          // defer-max (T13)
      float mnew = fmaxf(mrun, pmax);
      float corr = exp2f(mrun - mnew);
      acc_l *= corr;
#pragma unroll
      for (int mt = 0; mt < 8; ++mt) acc[mt] *= corr;
      mrun = mnew;
    }

    float pv[4][4];
#pragma unroll
    for (int t = 0; t < 4; ++t) {
      pv[t][0] = exp2f(st[t][0] - mrun);
      pv[t][1] = exp2f(st[t][1] - mrun);
      pv[t][2] = exp2f(st[t][2] - mrun);
      pv[t][3] = exp2f(st[t][3] - mrun);
    }

    // pack P^T to per-wave LDS: row q=l15 (128B, swizzled), col kv
#pragma unroll
    for (int t = 0; t < 4; ++t) {
      uint2 w;
      w.x = cvt_pk_bf16(pv[t][0], pv[t][1]);
      w.y = cvt_pk_bf16(pv[t][2], pv[t][3]);
      *(uint2*)(ps + ((t * 32 + g * 8) ^ swz)) = w;
    }

    // out^T += V^T * P^T ; lsum via ones-MFMA (auto-rescaled with acc)
#pragma unroll
    for (int k2 = 0; k2 < 2; ++k2) {
      bf16x8 pfr = *(const bf16x8*)(ps + ((k2 * 64 + g * 16) ^ swz));
      acc_l = __builtin_amdgcn_mfma_f32_16x16x32_bf16(ones, pfr, acc_l, 0, 0, 0);
#pragma unroll
      for (int mt = 0; mt < 8; ++mt) {
        bf16x8 a = *(const bf16x8*)(vsA + mt * 2048 + ((k2 * 64 + g * 16) ^ swz));
        acc[mt] = __builtin_amdgcn_mfma_f32_16x16x32_bf16(a, pfr, acc[mt], 0, 0, 0);
      }
    }
  }

  float inv = 1.f / acc_l[0];
  int b = bh >> 4, h = bh & 15;
  int sq = qt * 64 + wave * 16 + l15;
  unsigned short* orow = Out + ((size_t)(b * 1024 + sq) * 16 + h) * 128;
#pragma unroll
  for (int mt = 0; mt < 8; ++mt) {
    uint2 w;
    w.x = cvt_pk_bf16(acc[mt][0] * inv, acc[mt][1] * inv);
    w.y = cvt_pk_bf16(acc[mt][2] * inv, acc[mt][3] * inv);
    *(uint2*)(orow + mt * 16 + g * 4) = w;
  }
}

// ---------------------------------------------------------------------------
extern "C" void kernel_launch(void* const* d_in, const int* in_sizes, int n_in,
                              void* d_out, int out_size, void* d_ws, size_t ws_size,
                              hipStream_t stream) {
  const float* x       = (const float*)d_in[0];
  const float* cache_k = (const float*)d_in[1];
  const float* cache_v = (const float*)d_in[2];
  const float* w_qkv   = (const float*)d_in[3];
  const float* w_o     = (const float*)d_in[4];
  float* out = (float*)d_out;

  // workspace layout (~176.5 MiB)
  char* W = (char*)d_ws;
  constexpr size_t O_TRIG = 0;                       // 2 * 256KB
  constexpr size_t O_XB   = 524288;                  // 16MB (reused as attn_out)
  constexpr size_t O_WQT  = O_XB  + 16777216;        // 24MB
  constexpr size_t O_WOT  = O_WQT + 25165824;        // 8MB
  constexpr size_t O_QKV  = O_WOT + 8388608;         // 48MB
  constexpr size_t O_QB   = O_QKV + 50331648;        // 16MB
  constexpr size_t O_KF   = O_QB  + 16777216;        // 32MB
  constexpr size_t O_VT   = O_KF  + 33554432;        // 32MB
  float* cs_tab = (float*)(W + O_TRIG);
  float* sn_tab = (float*)(W + O_TRIG + 262144);
  unsigned short* xb   = (unsigned short*)(W + O_XB);
  unsigned short* wqT  = (unsigned short*)(W + O_WQT);
  unsigned short* woT  = (unsigned short*)(W + O_WOT);
  unsigned short* qkv  = (unsigned short*)(W + O_QKV);
  unsigned short* qb   = (unsigned short*)(W + O_QB);
  unsigned short* Kf   = (unsigned short*)(W + O_KF);
  unsigned short* Vt   = (unsigned short*)(W + O_VT);
  unsigned short* attn_out = xb;   // xb dead after gemm1

  build_trig<<<256, 256, 0, stream>>>(cs_tab, sn_tab);
  conv_bf16<<<4096, 256, 0, stream>>>(x, xb);                       // 8.4M elems
  transpose_conv<<<dim3(192, 64), 256, 0, stream>>>(w_qkv, wqT, 2048, 6144);
  transpose_conv<<<dim3(64, 64), 256, 0, stream>>>(w_o, woT, 2048, 2048);
  gemm_ring<4096, 6144, 2048, true><<<768, 512, 0, stream>>>(xb, wqT, qkv);
  rope_qk<<<4096, 256, 0, stream>>>(qkv, cs_tab, sn_tab, qb, Kf);
  copy_k<<<8192, 256, 0, stream>>>(cache_k, Kf);
  build_vt<<<dim3(64, 4, 64), 256, 0, stream>>>(cache_v, qkv, Vt);
  attn_kernel<<<1024, 256, 0, stream>>>(qb, Kf, Vt, attn_out);
  gemm_ring<4096, 2048, 2048, false><<<256, 512, 0, stream>>>(attn_out, woT, out);
}

// Round 5
// 335.701 us; speedup vs baseline: 1.2271x; 1.0702x over previous
//
#include <hip/hip_runtime.h>

// ---------------------------------------------------------------------------
// Attention layer: qkv proj -> RoPE -> concat KV cache -> softmax attn -> out proj
// B=4 Sq=1024 Skv_cache=1024 H=16 D=128 D_MODEL=2048
// bf16 MFMA everywhere. GEMMs: ring-3 counted-vmcnt pipeline (T3+T4+T5).
// Flash attention: LDS-BW-bound -> each wave owns 32 q rows (2 B-frag sets
// per K/V A-frag read), double-buffered K/V with counted vmcnt.
// ---------------------------------------------------------------------------

typedef __bf16 bf16x8 __attribute__((ext_vector_type(8)));
typedef float f32x4 __attribute__((ext_vector_type(4)));
typedef unsigned short u16x8 __attribute__((ext_vector_type(8)));
typedef unsigned short u16x4 __attribute__((ext_vector_type(4)));

__device__ __forceinline__ float b2f(unsigned short u) {
  return __builtin_bit_cast(float, (unsigned int)u << 16);
}
__device__ __forceinline__ unsigned short f2b(float f) {
  unsigned int x = __builtin_bit_cast(unsigned int, f);
  x += 0x7fffu + ((x >> 16) & 1u);   // RNE (finite values only)
  return (unsigned short)(x >> 16);
}
__device__ __forceinline__ unsigned int cvt_pk_bf16(float lo, float hi) {
  unsigned int r;
  asm("v_cvt_pk_bf16_f32 %0, %1, %2" : "=v"(r) : "v"(lo), "v"(hi));
  return r;
}
__device__ __forceinline__ void gload_lds16(const void* g, void* l) {
  __builtin_amdgcn_global_load_lds(
      (__attribute__((address_space(1))) void*)(g),
      (__attribute__((address_space(3))) void*)(l), 16, 0, 0);
}
__device__ __forceinline__ void barrier_nodrain() {
  asm volatile("" ::: "memory");
  __builtin_amdgcn_s_barrier();
  asm volatile("" ::: "memory");
}

// ---------------- trig table: cos/sin of (1024+s)*theta^(-i/64) ------------
__global__ void build_trig(float* __restrict__ cs, float* __restrict__ sn) {
  int idx = blockIdx.x * 256 + threadIdx.x;   // 65536 = 1024 s * 64 i
  int s = idx >> 6, i = idx & 63;
  float inv = exp2f(-(float)i * (13.287712379549449f / 64.0f)); // 10000^(-i/64)
  float ang = (float)(1024 + s) * inv;
  cs[idx] = cosf(ang);
  sn[idx] = sinf(ang);
}

// ---------------- f32 -> bf16 convert (8/thread) ---------------------------
__global__ void conv_bf16(const float* __restrict__ in, unsigned short* __restrict__ out) {
  size_t i = ((size_t)blockIdx.x * 256 + threadIdx.x) * 8;
  float4 a = *(const float4*)(in + i);
  float4 b = *(const float4*)(in + i + 4);
  u16x8 v;
  v[0] = f2b(a.x); v[1] = f2b(a.y); v[2] = f2b(a.z); v[3] = f2b(a.w);
  v[4] = f2b(b.x); v[5] = f2b(b.y); v[6] = f2b(b.z); v[7] = f2b(b.w);
  *(u16x8*)(out + i) = v;
}

// ---------------- transposed convert: in[R][C] f32 -> out[C][R] bf16 -------
__global__ __launch_bounds__(256) void transpose_conv(
    const float* __restrict__ in, unsigned short* __restrict__ out, int R, int C) {
  __shared__ float tile[32][33];
  int c0 = blockIdx.x * 32, r0 = blockIdx.y * 32;
  int tx = threadIdx.x & 31, ty = threadIdx.x >> 5;   // 32 x 8
#pragma unroll
  for (int j = 0; j < 4; ++j)
    tile[ty + j * 8][tx] = in[(size_t)(r0 + ty + j * 8) * C + c0 + tx];
  __syncthreads();
#pragma unroll
  for (int j = 0; j < 4; ++j)
    out[(size_t)(c0 + ty + j * 8) * R + r0 + tx] = f2b(tile[tx][ty + j * 8]);
}

// ---------------- cache_k f32 -> K_full[:, :1024] bf16 ---------------------
__global__ void copy_k(const float* __restrict__ ck, unsigned short* __restrict__ Kf) {
  size_t idx = ((size_t)blockIdx.x * 256 + threadIdx.x) * 4;  // over 64*1024*128
  size_t bh = idx >> 17, rem = idx & 131071;                  // 1024*128 = 2^17
  float4 a = *(const float4*)(ck + idx);
  u16x4 v;
  v[0] = f2b(a.x); v[1] = f2b(a.y); v[2] = f2b(a.z); v[3] = f2b(a.w);
  *(u16x4*)(Kf + bh * 262144 + rem) = v;                      // 2048*128 row block
}

// ---------------- RoPE q,k from qkv; q scaled by log2e/sqrt(128) -----------
__global__ __launch_bounds__(256) void rope_qk(
    const unsigned short* __restrict__ qkv, const float* __restrict__ cs,
    const float* __restrict__ sn, unsigned short* __restrict__ Qb,
    unsigned short* __restrict__ Kf) {
  int row = blockIdx.x;                 // b*1024 + s
  int b = row >> 10, s = row & 1023;
#pragma unroll
  for (int it = 0; it < 4; ++it) {
    int item = it * 256 + threadIdx.x;  // 16 heads * 64 pairs
    int h = item >> 6, i = item & 63;
    const unsigned short* base = qkv + (size_t)row * 6144 + h * 384;
    float q1 = b2f(base[i]),       q2 = b2f(base[64 + i]);
    float k1 = b2f(base[128 + i]), k2 = b2f(base[192 + i]);
    float c = cs[s * 64 + i], sv = sn[s * 64 + i];
    const float scale = 0.12751738f;    // log2(e)/sqrt(128): softmax in base-2
    size_t bh = (size_t)(b * 16 + h);
    unsigned short* qd = Qb + (bh * 1024 + s) * 128;
    qd[i]      = f2b((q1 * c - q2 * sv) * scale);
    qd[64 + i] = f2b((q2 * c + q1 * sv) * scale);
    unsigned short* kd = Kf + (bh * 2048 + 1024 + s) * 128;
    kd[i]      = f2b(k1 * c - k2 * sv);
    kd[64 + i] = f2b(k2 * c + k1 * sv);
  }
}

// ---------------- V^T build: V_t[b][h][d][s], s<1024 from cache, else qkv --
__global__ __launch_bounds__(256) void build_vt(
    const float* __restrict__ cv, const unsigned short* __restrict__ qkv,
    unsigned short* __restrict__ Vt) {
  __shared__ float tile[32][33];
  int bhid = blockIdx.z;
  int s0 = blockIdx.x * 32, d0 = blockIdx.y * 32;
  int tx = threadIdx.x & 31, ty = threadIdx.x >> 5;
  int b = bhid >> 4, h = bhid & 15;
#pragma unroll
  for (int j = 0; j < 4; ++j) {
    int s = s0 + ty + j * 8, d = d0 + tx;
    float v;
    if (s < 1024) v = cv[((size_t)bhid * 1024 + s) * 128 + d];
    else v = b2f(qkv[((size_t)b * 1024 + (s - 1024)) * 6144 + h * 384 + 256 + d]);
    tile[ty + j * 8][tx] = v;
  }
  __syncthreads();
#pragma unroll
  for (int j = 0; j < 4; ++j) {
    int d = d0 + ty + j * 8, s = s0 + tx;
    Vt[((size_t)bhid * 128 + d) * 2048 + s] = f2b(tile[tx][ty + j * 8]);
  }
}

// ---------------- GEMM: C[M][N] = A[M][K] * B^T  (B given as [N][K]) -------
// Ring-3 counted-vmcnt pipeline. BM=256 BN=128 BK=32, 8 waves (4M x 2N),
// per-wave 64x64 (4x4 16x16x32 frags). LDS: 3 slots x (A 16KB + B 8KB) = 72KB
// -> 2 blocks/CU. Ledger: at tile t, outstanding = {t+1,t+2} = 6 loads;
// vmcnt(3) completes tile t+1; next barrier certifies it block-wide. Slot
// (t+2)%3 was last read at tile t-1 (reads done before this barrier).
template <int M, int N, int K, bool OUT_BF16>
__global__ __launch_bounds__(512, 4) void gemm_ring(
    const unsigned short* __restrict__ A, const unsigned short* __restrict__ B,
    void* __restrict__ Cout) {
  __shared__ __align__(16) char lds[3 * 24576];
  constexpr int NT = N / 128;
  constexpr int Kt = K / 32;
  int bid = blockIdx.x;
  int tm = bid / NT, tn = bid % NT;
  int tid = threadIdx.x;
  int lane = tid & 63, wave = tid >> 6;
  int wr = (wave >> 1) * 64, wc = (wave & 1) * 64;
  int l15 = lane & 15, g = lane >> 4;

  int p = tid * 16;   // byte position in a 16KB/8KB staging region
  const unsigned short* aSrc0 = A + (size_t)(tm * 256 + (p >> 6)) * K + ((p & 63) >> 1);
  const unsigned short* aSrc1 = aSrc0 + (size_t)128 * K;   // rows 128..255
  const unsigned short* bSrc  = B + (size_t)(tn * 128 + (p >> 6)) * K + ((p & 63) >> 1);

  f32x4 acc[4][4] = {};

  auto stage = [&](int s) {
    char* base = (char*)lds + s * 24576;
    gload_lds16(aSrc0, base + p);
    gload_lds16(aSrc1, base + 8192 + p);
    gload_lds16(bSrc,  base + 16384 + p);
    aSrc0 += 32; aSrc1 += 32; bSrc += 32;
  };

  stage(0);
  stage(1);
  asm volatile("s_waitcnt vmcnt(3)" ::: "memory");   // tile 0 complete (mine)

  int slot = 0, sNext = 2;
  for (int t = 0; t < Kt; ++t) {
    barrier_nodrain();                 // certifies tile t staged block-wide
    if (t + 2 < Kt) {
      stage(sNext);
      sNext = (sNext == 2) ? 0 : sNext + 1;
      asm volatile("s_waitcnt vmcnt(3)" ::: "memory");   // tile t+1 complete (mine)
    } else {
      asm volatile("s_waitcnt vmcnt(0)" ::: "memory");   // tail drain
    }
    const char* As_ = (const char*)lds + slot * 24576;
    const char* Bs_ = As_ + 16384;
    bf16x8 af[4], bfr[4];
#pragma unroll
    for (int m = 0; m < 4; ++m)
      af[m] = *(const bf16x8*)(As_ + (wr + m * 16 + l15) * 64 + g * 16);
#pragma unroll
    for (int n = 0; n < 4; ++n)
      bfr[n] = *(const bf16x8*)(Bs_ + (wc + n * 16 + l15) * 64 + g * 16);
    __builtin_amdgcn_s_setprio(1);
#pragma unroll
    for (int m = 0; m < 4; ++m)
#pragma unroll
      for (int n = 0; n < 4; ++n)
        acc[m][n] = __builtin_amdgcn_mfma_f32_16x16x32_bf16(af[m], bfr[n], acc[m][n], 0, 0, 0);
    __builtin_amdgcn_s_setprio(0);
    slot = (slot == 2) ? 0 : slot + 1;
  }

#pragma unroll
  for (int m = 0; m < 4; ++m) {
    int row0 = tm * 256 + wr + m * 16 + g * 4;
#pragma unroll
    for (int n = 0; n < 4; ++n) {
      int col = tn * 128 + wc + n * 16 + l15;
#pragma unroll
      for (int r = 0; r < 4; ++r) {
        size_t off = (size_t)(row0 + r) * N + col;
        if constexpr (OUT_BF16) ((unsigned short*)Cout)[off] = f2b(acc[m][n][r]);
        else ((float*)Cout)[off] = acc[m][n][r];
      }
    }
  }
}

// ---------------- Flash attention ------------------------------------------
// grid = 512: bh (64) x q-tile (8 of 128 rows). 4 waves x 32 q rows each
// (2 q-sets of 16 per wave -> each K/V A-frag LDS read feeds 2 MFMAs; the
// kernel was LDS-BW-bound at q=16). Double-buffered K/V, counted vmcnt(8).
__global__ __launch_bounds__(256, 2) void attn_kernel(
    const unsigned short* __restrict__ Qb,   // [64][1024][128], pre-scaled
    const unsigned short* __restrict__ Kf,   // [64][2048][128]
    const unsigned short* __restrict__ Vt,   // [64][128][2048]
    unsigned short* __restrict__ Out) {      // [4096][2048] = [b][s][h*128+d]
  __shared__ __align__(16) unsigned short Ks[2][64 * 128];  // 2x16KB, swizzled
  __shared__ __align__(16) unsigned short Vs[2][64 * 128];  // 2x16KB, swizzled
  __shared__ __align__(16) char PsRaw[4 * 2 * 2048];        // 16KB: wave, qset
  // total LDS = 81920 -> exactly 2 blocks/CU

  int raw = blockIdx.x;
  int sb = (raw & 7) * 64 + (raw >> 3);     // XCD swizzle: 8 heads per XCD
  int bh = sb >> 3, qt = sb & 7;
  int tid = threadIdx.x, lane = tid & 63, wave = tid >> 6;
  int l15 = lane & 15, g = lane >> 4;
  int swz = (l15 & 7) << 4;

  int qrow0 = qt * 128 + wave * 32;
  bf16x8 qf0[4], qf1[4];
  const unsigned short* qp0 = Qb + ((size_t)(bh * 1024 + qrow0 + l15)) * 128;
#pragma unroll
  for (int kk = 0; kk < 4; ++kk) {
    qf0[kk] = *(const bf16x8*)(qp0 + kk * 32 + g * 8);
    qf1[kk] = *(const bf16x8*)(qp0 + 16 * 128 + kk * 32 + g * 8);
  }

  u16x8 ou;
#pragma unroll
  for (int j = 0; j < 8; ++j) ou[j] = 0x3F80;           // bf16 1.0
  bf16x8 ones = __builtin_bit_cast(bf16x8, ou);

  // hoisted staging pointers (incremented per kv-tile)
  const unsigned short* Kbase = Kf + (size_t)bh * 2048 * 128;
  const unsigned short* Vbase = Vt + (size_t)bh * 128 * 2048;
  const unsigned short* kptr[4];
  const unsigned short* vptr[4];
  char* kdst0[4];
  char* vdst0[4];
#pragma unroll
  for (int is = 0; is < 4; ++is) {
    int p = tid * 16 + is * 4096;
    int lgk = p ^ (((p >> 8) & 7) << 4);          // K rows = 256B
    kptr[is] = Kbase + (size_t)(lgk >> 8) * 128 + ((lgk & 255) >> 1);
    kdst0[is] = (char*)Ks + is * 4096 + (tid & 192) * 16;
    int lgv = p ^ (((p >> 7) & 7) << 4);          // V^T rows = 128B
    vptr[is] = Vbase + (size_t)(lgv >> 7) * 2048 + ((lgv & 127) >> 1);
    vdst0[is] = (char*)Vs + is * 4096 + (tid & 192) * 16;
  }
  char* ps0 = PsRaw + wave * 4096 + l15 * 128;
  char* ps1 = ps0 + 2048;

  auto stage = [&](int buf) {
#pragma unroll
    for (int is = 0; is < 4; ++is) {
      gload_lds16(kptr[is], kdst0[is] + buf * 16384);  kptr[is] += 64 * 128;
      gload_lds16(vptr[is], vdst0[is] + buf * 16384);  vptr[is] += 64;
    }
  };

  float mrun0 = -1e30f, mrun1 = -1e30f;
  f32x4 acc0[8] = {}, acc1[8] = {};
  f32x4 accl0 = {}, accl1 = {};

  // softmax+pack for one q-set (all loops unrolled -> static indexing)
  auto softmax_pack = [&](f32x4* st, float& mrun, f32x4* accp, f32x4& accl,
                          char* ps) {
    float m0 = fmaxf(fmaxf(st[0][0], st[0][1]), st[0][2]);
    float m1 = fmaxf(fmaxf(st[0][3], st[1][0]), st[1][1]);
    float m2 = fmaxf(fmaxf(st[1][2], st[1][3]), st[2][0]);
    float m3 = fmaxf(fmaxf(st[2][1], st[2][2]), st[2][3]);
    float m4 = fmaxf(fmaxf(st[3][0], st[3][1]), st[3][2]);
    float pmax = fmaxf(fmaxf(fmaxf(m0, m1), fmaxf(m2, m3)), fmaxf(m4, st[3][3]));
    pmax = fmaxf(pmax, __shfl_xor(pmax, 16));
    pmax = fmaxf(pmax, __shfl_xor(pmax, 32));
    if (!__all(pmax - mrun <= 8.0f)) {          // defer-max (T13)
      float mnew = fmaxf(mrun, pmax);
      float corr = exp2f(mrun - mnew);
      accl *= corr;
#pragma unroll
      for (int mt = 0; mt < 8; ++mt) accp[mt] *= corr;
      mrun = mnew;
    }
#pragma unroll
    for (int t = 0; t < 4; ++t) {
      float p0 = exp2f(st[t][0] - mrun);
      float p1 = exp2f(st[t][1] - mrun);
      float p2 = exp2f(st[t][2] - mrun);
      float p3 = exp2f(st[t][3] - mrun);
      uint2 w;
      w.x = cvt_pk_bf16(p0, p1);
      w.y = cvt_pk_bf16(p2, p3);
      *(uint2*)(ps + ((t * 32 + g * 8) ^ swz)) = w;
    }
  };

  stage(0);
  for (int it = 0; it < 32; ++it) {
    int cur = it & 1;
    barrier_nodrain();          // prev compute done -> buf cur^1 reads retired
    if (it + 1 < 32) {
      stage(cur ^ 1);
      asm volatile("s_waitcnt vmcnt(8)" ::: "memory");  // tile it arrived (mine)
    } else {
      asm volatile("s_waitcnt vmcnt(0)" ::: "memory");  // tail drain
    }
    barrier_nodrain();          // tile it visible block-wide
    const char* ksA = (const char*)Ks + cur * 16384 + l15 * 256;
    const char* vsA = (const char*)Vs + cur * 16384 + l15 * 128;

    // S^T tiles: 4 x (16 kv x 16 q) x 2 q-sets; one A-read feeds 2 MFMAs
    f32x4 st0[4] = {}, st1[4] = {};
#pragma unroll
    for (int kk = 0; kk < 4; ++kk) {
#pragma unroll
      for (int t = 0; t < 4; ++t) {
        bf16x8 a = *(const bf16x8*)(ksA + t * 4096 + ((kk * 64 + g * 16) ^ swz));
        st0[t] = __builtin_amdgcn_mfma_f32_16x16x32_bf16(a, qf0[kk], st0[t], 0, 0, 0);
        st1[t] = __builtin_amdgcn_mfma_f32_16x16x32_bf16(a, qf1[kk], st1[t], 0, 0, 0);
      }
    }

    softmax_pack(st0, mrun0, acc0, accl0, ps0);
    softmax_pack(st1, mrun1, acc1, accl1, ps1);

    // out^T += V^T * P^T (both q-sets per V A-read); lsum via ones-MFMA
#pragma unroll
    for (int k2 = 0; k2 < 2; ++k2) {
      bf16x8 p0 = *(const bf16x8*)(ps0 + ((k2 * 64 + g * 16) ^ swz));
      bf16x8 p1 = *(const bf16x8*)(ps1 + ((k2 * 64 + g * 16) ^ swz));
      accl0 = __builtin_amdgcn_mfma_f32_16x16x32_bf16(ones, p0, accl0, 0, 0, 0);
      accl1 = __builtin_amdgcn_mfma_f32_16x16x32_bf16(ones, p1, accl1, 0, 0, 0);
#pragma unroll
      for (int mt = 0; mt < 8; ++mt) {
        bf16x8 a = *(const bf16x8*)(vsA + mt * 2048 + ((k2 * 64 + g * 16) ^ swz));
        acc0[mt] = __builtin_amdgcn_mfma_f32_16x16x32_bf16(a, p0, acc0[mt], 0, 0, 0);
        acc1[mt] = __builtin_amdgcn_mfma_f32_16x16x32_bf16(a, p1, acc1[mt], 0, 0, 0);
      }
    }
  }

  float inv0 = 1.f / accl0[0];
  float inv1 = 1.f / accl1[0];
  int b = bh >> 4, h = bh & 15;
  int sq = qt * 128 + wave * 32 + l15;
  unsigned short* orow0 = Out + ((size_t)(b * 1024 + sq) * 16 + h) * 128;
  unsigned short* orow1 = orow0 + (size_t)16 * 2048;
#pragma unroll
  for (int mt = 0; mt < 8; ++mt) {
    uint2 w0, w1;
    w0.x = cvt_pk_bf16(acc0[mt][0] * inv0, acc0[mt][1] * inv0);
    w0.y = cvt_pk_bf16(acc0[mt][2] * inv0, acc0[mt][3] * inv0);
    w1.x = cvt_pk_bf16(acc1[mt][0] * inv1, acc1[mt][1] * inv1);
    w1.y = cvt_pk_bf16(acc1[mt][2] * inv1, acc1[mt][3] * inv1);
    *(uint2*)(orow0 + mt * 16 + g * 4) = w0;
    *(uint2*)(orow1 + mt * 16 + g * 4) = w1;
  }
}

// ---------------------------------------------------------------------------
extern "C" void kernel_launch(void* const* d_in, const int* in_sizes, int n_in,
                              void* d_out, int out_size, void* d_ws, size_t ws_size,
                              hipStream_t stream) {
  const float* x       = (const float*)d_in[0];
  const float* cache_k = (const float*)d_in[1];
  const float* cache_v = (const float*)d_in[2];
  const float* w_qkv   = (const float*)d_in[3];
  const float* w_o     = (const float*)d_in[4];
  float* out = (float*)d_out;

  // workspace layout (~176.5 MiB)
  char* W = (char*)d_ws;
  constexpr size_t O_TRIG = 0;                       // 2 * 256KB
  constexpr size_t O_XB   = 524288;                  // 16MB (reused as attn_out)
  constexpr size_t O_WQT  = O_XB  + 16777216;        // 24MB
  constexpr size_t O_WOT  = O_WQT + 25165824;        // 8MB
  constexpr size_t O_QKV  = O_WOT + 8388608;         // 48MB
  constexpr size_t O_QB   = O_QKV + 50331648;        // 16MB
  constexpr size_t O_KF   = O_QB  + 16777216;        // 32MB
  constexpr size_t O_VT   = O_KF  + 33554432;        // 32MB
  float* cs_tab = (float*)(W + O_TRIG);
  float* sn_tab = (float*)(W + O_TRIG + 262144);
  unsigned short* xb   = (unsigned short*)(W + O_XB);
  unsigned short* wqT  = (unsigned short*)(W + O_WQT);
  unsigned short* woT  = (unsigned short*)(W + O_WOT);
  unsigned short* qkv  = (unsigned short*)(W + O_QKV);
  unsigned short* qb   = (unsigned short*)(W + O_QB);
  unsigned short* Kf   = (unsigned short*)(W + O_KF);
  unsigned short* Vt   = (unsigned short*)(W + O_VT);
  unsigned short* attn_out = xb;   // xb dead after gemm1

  build_trig<<<256, 256, 0, stream>>>(cs_tab, sn_tab);
  conv_bf16<<<4096, 256, 0, stream>>>(x, xb);                       // 8.4M elems
  transpose_conv<<<dim3(192, 64), 256, 0, stream>>>(w_qkv, wqT, 2048, 6144);
  transpose_conv<<<dim3(64, 64), 256, 0, stream>>>(w_o, woT, 2048, 2048);
  gemm_ring<4096, 6144, 2048, true><<<768, 512, 0, stream>>>(xb, wqT, qkv);
  rope_qk<<<4096, 256, 0, stream>>>(qkv, cs_tab, sn_tab, qb, Kf);
  copy_k<<<8192, 256, 0, stream>>>(cache_k, Kf);
  build_vt<<<dim3(64, 4, 64), 256, 0, stream>>>(cache_v, qkv, Vt);
  attn_kernel<<<512, 256, 0, stream>>>(qb, Kf, Vt, attn_out);
  gemm_ring<4096, 2048, 2048, false><<<256, 512, 0, stream>>>(attn_out, woT, out);
}

// Round 6
// 332.976 us; speedup vs baseline: 1.2372x; 1.0082x over previous
//
#include <hip/hip_runtime.h>

// ---------------------------------------------------------------------------
// Attention layer: qkv proj -> RoPE -> concat KV cache -> softmax attn -> out proj
// B=4 Sq=1024 Skv_cache=1024 H=16 D=128 D_MODEL=2048
// bf16 MFMA everywhere. GEMMs: ring-2 counted-vmcnt, BK=64, XOR-swizzled LDS
// (conflict-free ds_read_b128). Flash attention: 32 q rows/wave, dbuf K/V.
// ---------------------------------------------------------------------------

typedef __bf16 bf16x8 __attribute__((ext_vector_type(8)));
typedef float f32x4 __attribute__((ext_vector_type(4)));
typedef unsigned short u16x8 __attribute__((ext_vector_type(8)));
typedef unsigned short u16x4 __attribute__((ext_vector_type(4)));

__device__ __forceinline__ float b2f(unsigned short u) {
  return __builtin_bit_cast(float, (unsigned int)u << 16);
}
__device__ __forceinline__ unsigned short f2b(float f) {
  unsigned int x = __builtin_bit_cast(unsigned int, f);
  x += 0x7fffu + ((x >> 16) & 1u);   // RNE (finite values only)
  return (unsigned short)(x >> 16);
}
__device__ __forceinline__ unsigned int cvt_pk_bf16(float lo, float hi) {
  unsigned int r;
  asm("v_cvt_pk_bf16_f32 %0, %1, %2" : "=v"(r) : "v"(lo), "v"(hi));
  return r;
}
__device__ __forceinline__ void gload_lds16(const void* g, void* l) {
  __builtin_amdgcn_global_load_lds(
      (__attribute__((address_space(1))) void*)(g),
      (__attribute__((address_space(3))) void*)(l), 16, 0, 0);
}
__device__ __forceinline__ void barrier_nodrain() {
  asm volatile("" ::: "memory");
  __builtin_amdgcn_s_barrier();
  asm volatile("" ::: "memory");
}

// ---------------- trig table: cos/sin of (1024+s)*theta^(-i/64) ------------
__global__ void build_trig(float* __restrict__ cs, float* __restrict__ sn) {
  int idx = blockIdx.x * 256 + threadIdx.x;   // 65536 = 1024 s * 64 i
  int s = idx >> 6, i = idx & 63;
  float inv = exp2f(-(float)i * (13.287712379549449f / 64.0f)); // 10000^(-i/64)
  float ang = (float)(1024 + s) * inv;
  cs[idx] = cosf(ang);
  sn[idx] = sinf(ang);
}

// ---------------- f32 -> bf16 convert (8/thread) ---------------------------
__global__ void conv_bf16(const float* __restrict__ in, unsigned short* __restrict__ out) {
  size_t i = ((size_t)blockIdx.x * 256 + threadIdx.x) * 8;
  float4 a = *(const float4*)(in + i);
  float4 b = *(const float4*)(in + i + 4);
  u16x8 v;
  v[0] = f2b(a.x); v[1] = f2b(a.y); v[2] = f2b(a.z); v[3] = f2b(a.w);
  v[4] = f2b(b.x); v[5] = f2b(b.y); v[6] = f2b(b.z); v[7] = f2b(b.w);
  *(u16x8*)(out + i) = v;
}

// ---------------- transposed convert: in[R][C] f32 -> out[C][R] bf16 -------
__global__ __launch_bounds__(256) void transpose_conv(
    const float* __restrict__ in, unsigned short* __restrict__ out, int R, int C) {
  __shared__ float tile[32][33];
  int c0 = blockIdx.x * 32, r0 = blockIdx.y * 32;
  int tx = threadIdx.x & 31, ty = threadIdx.x >> 5;   // 32 x 8
#pragma unroll
  for (int j = 0; j < 4; ++j)
    tile[ty + j * 8][tx] = in[(size_t)(r0 + ty + j * 8) * C + c0 + tx];
  __syncthreads();
#pragma unroll
  for (int j = 0; j < 4; ++j)
    out[(size_t)(c0 + ty + j * 8) * R + r0 + tx] = f2b(tile[tx][ty + j * 8]);
}

// ---------------- cache_k f32 -> K_full[:, :1024] bf16 ---------------------
__global__ void copy_k(const float* __restrict__ ck, unsigned short* __restrict__ Kf) {
  size_t idx = ((size_t)blockIdx.x * 256 + threadIdx.x) * 4;  // over 64*1024*128
  size_t bh = idx >> 17, rem = idx & 131071;                  // 1024*128 = 2^17
  float4 a = *(const float4*)(ck + idx);
  u16x4 v;
  v[0] = f2b(a.x); v[1] = f2b(a.y); v[2] = f2b(a.z); v[3] = f2b(a.w);
  *(u16x4*)(Kf + bh * 262144 + rem) = v;                      // 2048*128 row block
}

// ---------------- RoPE q,k from qkv; q scaled by log2e/sqrt(128) -----------
__global__ __launch_bounds__(256) void rope_qk(
    const unsigned short* __restrict__ qkv, const float* __restrict__ cs,
    const float* __restrict__ sn, unsigned short* __restrict__ Qb,
    unsigned short* __restrict__ Kf) {
  int row = blockIdx.x;                 // b*1024 + s
  int b = row >> 10, s = row & 1023;
#pragma unroll
  for (int it = 0; it < 4; ++it) {
    int item = it * 256 + threadIdx.x;  // 16 heads * 64 pairs
    int h = item >> 6, i = item & 63;
    const unsigned short* base = qkv + (size_t)row * 6144 + h * 384;
    float q1 = b2f(base[i]),       q2 = b2f(base[64 + i]);
    float k1 = b2f(base[128 + i]), k2 = b2f(base[192 + i]);
    float c = cs[s * 64 + i], sv = sn[s * 64 + i];
    const float scale = 0.12751738f;    // log2(e)/sqrt(128): softmax in base-2
    size_t bh = (size_t)(b * 16 + h);
    unsigned short* qd = Qb + (bh * 1024 + s) * 128;
    qd[i]      = f2b((q1 * c - q2 * sv) * scale);
    qd[64 + i] = f2b((q2 * c + q1 * sv) * scale);
    unsigned short* kd = Kf + (bh * 2048 + 1024 + s) * 128;
    kd[i]      = f2b(k1 * c - k2 * sv);
    kd[64 + i] = f2b(k2 * c + k1 * sv);
  }
}

// ---------------- V^T build: V_t[b][h][d][s], s<1024 from cache, else qkv --
__global__ __launch_bounds__(256) void build_vt(
    const float* __restrict__ cv, const unsigned short* __restrict__ qkv,
    unsigned short* __restrict__ Vt) {
  __shared__ float tile[32][33];
  int bhid = blockIdx.z;
  int s0 = blockIdx.x * 32, d0 = blockIdx.y * 32;
  int tx = threadIdx.x & 31, ty = threadIdx.x >> 5;
  int b = bhid >> 4, h = bhid & 15;
#pragma unroll
  for (int j = 0; j < 4; ++j) {
    int s = s0 + ty + j * 8, d = d0 + tx;
    float v;
    if (s < 1024) v = cv[((size_t)bhid * 1024 + s) * 128 + d];
    else v = b2f(qkv[((size_t)b * 1024 + (s - 1024)) * 6144 + h * 384 + 256 + d]);
    tile[ty + j * 8][tx] = v;
  }
  __syncthreads();
#pragma unroll
  for (int j = 0; j < 4; ++j) {
    int d = d0 + ty + j * 8, s = s0 + tx;
    Vt[((size_t)bhid * 128 + d) * 2048 + s] = f2b(tile[tx][ty + j * 8]);
  }
}

// ---------------- GEMM: C[M][N] = A[M][K] * B^T  (B given as [N][K]) -------
// Ring-2 counted-vmcnt, BM=256 BN=128 BK=64, 8 waves (4M x 2N), per-wave
// 64x64. LDS slot = A[256][128B] 32KB + B[128][128B] 16KB, XOR-swizzled
// (c ^= (row&7)<<4): a 16-lane frag-read group hits all 32 banks ->
// conflict-free ds_read_b128. gload_lds dest linear; source pre-inverse-
// swizzled (same involution). Ledger: stage = 6 loads; at iter t outstanding
// = {t,t+1} = 12, vmcnt(6) -> tile t arrived; barrier certifies block-wide.
// Buf (t+1)&1 last read at iter t-1, whose reads completed before this
// iter's first barrier.
template <int M, int N, int K, bool OUT_BF16>
__global__ __launch_bounds__(512, 2) void gemm_ring(
    const unsigned short* __restrict__ A, const unsigned short* __restrict__ B,
    void* __restrict__ Cout) {
  __shared__ __align__(16) char lds[2 * 49152];   // 96KB -> 1 block/CU
  constexpr int NT = N / 128;
  constexpr int Kt = K / 64;
  int bid = blockIdx.x;
  int tm = bid / NT, tn = bid % NT;
  int tid = threadIdx.x;
  int lane = tid & 63, wave = tid >> 6;
  int wr = (wave >> 1) * 64, wc = (wave & 1) * 64;
  int l15 = lane & 15, g = lane >> 4;
  int swz = (l15 & 7) << 4;

  // staging sources: A 2048 chunks (4/thread), B 1024 chunks (2/thread)
  const unsigned short* aS[4];
  const unsigned short* bS[2];
#pragma unroll
  for (int i = 0; i < 4; ++i) {
    int p = tid * 16 + i * 8192;
    int row = p >> 7, c = (p & 127) ^ ((row & 7) << 4);
    aS[i] = A + (size_t)(tm * 256 + row) * K + (c >> 1);
  }
#pragma unroll
  for (int i = 0; i < 2; ++i) {
    int p = tid * 16 + i * 8192;
    int row = p >> 7, c = (p & 127) ^ ((row & 7) << 4);
    bS[i] = B + (size_t)(tn * 128 + row) * K + (c >> 1);
  }

  f32x4 acc[4][4] = {};

  auto stage = [&](int s) {
    char* base = (char*)lds + s * 49152;
#pragma unroll
    for (int i = 0; i < 4; ++i) {
      gload_lds16(aS[i], base + tid * 16 + i * 8192);
      aS[i] += 64;
    }
#pragma unroll
    for (int i = 0; i < 2; ++i) {
      gload_lds16(bS[i], base + 32768 + tid * 16 + i * 8192);
      bS[i] += 64;
    }
  };

  stage(0);
  for (int t = 0; t < Kt; ++t) {
    int cur = t & 1;
    barrier_nodrain();               // prev compute done -> buf cur^1 free
    if (t + 1 < Kt) {
      stage(cur ^ 1);
      asm volatile("s_waitcnt vmcnt(6)" ::: "memory");   // tile t arrived (mine)
    } else {
      asm volatile("s_waitcnt vmcnt(0)" ::: "memory");   // tail drain
    }
    barrier_nodrain();               // tile t visible block-wide
    const char* As_ = (const char*)lds + cur * 49152;
    const char* Bs_ = As_ + 32768;
#pragma unroll
    for (int h = 0; h < 2; ++h) {
      bf16x8 af[4], bfr[4];
#pragma unroll
      for (int m = 0; m < 4; ++m)
        af[m] = *(const bf16x8*)(As_ + (wr + m * 16 + l15) * 128 +
                                 ((h * 64 + g * 16) ^ swz));
#pragma unroll
      for (int n = 0; n < 4; ++n)
        bfr[n] = *(const bf16x8*)(Bs_ + (wc + n * 16 + l15) * 128 +
                                  ((h * 64 + g * 16) ^ swz));
      __builtin_amdgcn_s_setprio(1);
#pragma unroll
      for (int m = 0; m < 4; ++m)
#pragma unroll
        for (int n = 0; n < 4; ++n)
          acc[m][n] = __builtin_amdgcn_mfma_f32_16x16x32_bf16(af[m], bfr[n], acc[m][n], 0, 0, 0);
      __builtin_amdgcn_s_setprio(0);
    }
  }

#pragma unroll
  for (int m = 0; m < 4; ++m) {
    int row0 = tm * 256 + wr + m * 16 + g * 4;
#pragma unroll
    for (int n = 0; n < 4; ++n) {
      int col = tn * 128 + wc + n * 16 + l15;
#pragma unroll
      for (int r = 0; r < 4; ++r) {
        size_t off = (size_t)(row0 + r) * N + col;
        if constexpr (OUT_BF16) ((unsigned short*)Cout)[off] = f2b(acc[m][n][r]);
        else ((float*)Cout)[off] = acc[m][n][r];
      }
    }
  }
}

// ---------------- Flash attention ------------------------------------------
// grid = 512: bh (64) x q-tile (8 of 128 rows). 4 waves x 32 q rows each
// (2 q-sets of 16 per wave -> each K/V A-frag LDS read feeds 2 MFMAs; the
// kernel was LDS-BW-bound at q=16). Double-buffered K/V, counted vmcnt(8).
__global__ __launch_bounds__(256, 2) void attn_kernel(
    const unsigned short* __restrict__ Qb,   // [64][1024][128], pre-scaled
    const unsigned short* __restrict__ Kf,   // [64][2048][128]
    const unsigned short* __restrict__ Vt,   // [64][128][2048]
    unsigned short* __restrict__ Out) {      // [4096][2048] = [b][s][h*128+d]
  __shared__ __align__(16) unsigned short Ks[2][64 * 128];  // 2x16KB, swizzled
  __shared__ __align__(16) unsigned short Vs[2][64 * 128];  // 2x16KB, swizzled
  __shared__ __align__(16) char PsRaw[4 * 2 * 2048];        // 16KB: wave, qset
  // total LDS = 81920 -> exactly 2 blocks/CU

  int raw = blockIdx.x;
  int sb = (raw & 7) * 64 + (raw >> 3);     // XCD swizzle: 8 heads per XCD
  int bh = sb >> 3, qt = sb & 7;
  int tid = threadIdx.x, lane = tid & 63, wave = tid >> 6;
  int l15 = lane & 15, g = lane >> 4;
  int swz = (l15 & 7) << 4;

  int qrow0 = qt * 128 + wave * 32;
  bf16x8 qf0[4], qf1[4];
  const unsigned short* qp0 = Qb + ((size_t)(bh * 1024 + qrow0 + l15)) * 128;
#pragma unroll
  for (int kk = 0; kk < 4; ++kk) {
    qf0[kk] = *(const bf16x8*)(qp0 + kk * 32 + g * 8);
    qf1[kk] = *(const bf16x8*)(qp0 + 16 * 128 + kk * 32 + g * 8);
  }

  u16x8 ou;
#pragma unroll
  for (int j = 0; j < 8; ++j) ou[j] = 0x3F80;           // bf16 1.0
  bf16x8 ones = __builtin_bit_cast(bf16x8, ou);

  // hoisted staging pointers (incremented per kv-tile)
  const unsigned short* Kbase = Kf + (size_t)bh * 2048 * 128;
  const unsigned short* Vbase = Vt + (size_t)bh * 128 * 2048;
  const unsigned short* kptr[4];
  const unsigned short* vptr[4];
  char* kdst0[4];
  char* vdst0[4];
#pragma unroll
  for (int is = 0; is < 4; ++is) {
    int p = tid * 16 + is * 4096;
    int lgk = p ^ (((p >> 8) & 7) << 4);          // K rows = 256B
    kptr[is] = Kbase + (size_t)(lgk >> 8) * 128 + ((lgk & 255) >> 1);
    kdst0[is] = (char*)Ks + is * 4096 + (tid & 192) * 16;
    int lgv = p ^ (((p >> 7) & 7) << 4);          // V^T rows = 128B
    vptr[is] = Vbase + (size_t)(lgv >> 7) * 2048 + ((lgv & 127) >> 1);
    vdst0[is] = (char*)Vs + is * 4096 + (tid & 192) * 16;
  }
  char* ps0 = PsRaw + wave * 4096 + l15 * 128;
  char* ps1 = ps0 + 2048;

  auto stage = [&](int buf) {
#pragma unroll
    for (int is = 0; is < 4; ++is) {
      gload_lds16(kptr[is], kdst0[is] + buf * 16384);  kptr[is] += 64 * 128;
      gload_lds16(vptr[is], vdst0[is] + buf * 16384);  vptr[is] += 64;
    }
  };

  float mrun0 = -1e30f, mrun1 = -1e30f;
  f32x4 acc0[8] = {}, acc1[8] = {};
  f32x4 accl0 = {}, accl1 = {};

  // softmax+pack for one q-set (all loops unrolled -> static indexing)
  auto softmax_pack = [&](f32x4* st, float& mrun, f32x4* accp, f32x4& accl,
                          char* ps) {
    float m0 = fmaxf(fmaxf(st[0][0], st[0][1]), st[0][2]);
    float m1 = fmaxf(fmaxf(st[0][3], st[1][0]), st[1][1]);
    float m2 = fmaxf(fmaxf(st[1][2], st[1][3]), st[2][0]);
    float m3 = fmaxf(fmaxf(st[2][1], st[2][2]), st[2][3]);
    float m4 = fmaxf(fmaxf(st[3][0], st[3][1]), st[3][2]);
    float pmax = fmaxf(fmaxf(fmaxf(m0, m1), fmaxf(m2, m3)), fmaxf(m4, st[3][3]));
    pmax = fmaxf(pmax, __shfl_xor(pmax, 16));
    pmax = fmaxf(pmax, __shfl_xor(pmax, 32));
    if (!__all(pmax - mrun <= 8.0f)) {          // defer-max (T13)
      float mnew = fmaxf(mrun, pmax);
      float corr = exp2f(mrun - mnew);
      accl *= corr;
#pragma unroll
      for (int mt = 0; mt < 8; ++mt) accp[mt] *= corr;
      mrun = mnew;
    }
#pragma unroll
    for (int t = 0; t < 4; ++t) {
      float p0 = exp2f(st[t][0] - mrun);
      float p1 = exp2f(st[t][1] - mrun);
      float p2 = exp2f(st[t][2] - mrun);
      float p3 = exp2f(st[t][3] - mrun);
      uint2 w;
      w.x = cvt_pk_bf16(p0, p1);
      w.y = cvt_pk_bf16(p2, p3);
      *(uint2*)(ps + ((t * 32 + g * 8) ^ swz)) = w;
    }
  };

  stage(0);
  for (int it = 0; it < 32; ++it) {
    int cur = it & 1;
    barrier_nodrain();          // prev compute done -> buf cur^1 reads retired
    if (it + 1 < 32) {
      stage(cur ^ 1);
      asm volatile("s_waitcnt vmcnt(8)" ::: "memory");  // tile it arrived (mine)
    } else {
      asm volatile("s_waitcnt vmcnt(0)" ::: "memory");  // tail drain
    }
    barrier_nodrain();          // tile it visible block-wide
    const char* ksA = (const char*)Ks + cur * 16384 + l15 * 256;
    const char* vsA = (const char*)Vs + cur * 16384 + l15 * 128;

    // S^T tiles: 4 x (16 kv x 16 q) x 2 q-sets; one A-read feeds 2 MFMAs
    f32x4 st0[4] = {}, st1[4] = {};
#pragma unroll
    for (int kk = 0; kk < 4; ++kk) {
#pragma unroll
      for (int t = 0; t < 4; ++t) {
        bf16x8 a = *(const bf16x8*)(ksA + t * 4096 + ((kk * 64 + g * 16) ^ swz));
        st0[t] = __builtin_amdgcn_mfma_f32_16x16x32_bf16(a, qf0[kk], st0[t], 0, 0, 0);
        st1[t] = __builtin_amdgcn_mfma_f32_16x16x32_bf16(a, qf1[kk], st1[t], 0, 0, 0);
      }
    }

    softmax_pack(st0, mrun0, acc0, accl0, ps0);
    softmax_pack(st1, mrun1, acc1, accl1, ps1);

    // out^T += V^T * P^T (both q-sets per V A-read); lsum via ones-MFMA
#pragma unroll
    for (int k2 = 0; k2 < 2; ++k2) {
      bf16x8 p0 = *(const bf16x8*)(ps0 + ((k2 * 64 + g * 16) ^ swz));
      bf16x8 p1 = *(const bf16x8*)(ps1 + ((k2 * 64 + g * 16) ^ swz));
      accl0 = __builtin_amdgcn_mfma_f32_16x16x32_bf16(ones, p0, accl0, 0, 0, 0);
      accl1 = __builtin_amdgcn_mfma_f32_16x16x32_bf16(ones, p1, accl1, 0, 0, 0);
#pragma unroll
      for (int mt = 0; mt < 8; ++mt) {
        bf16x8 a = *(const bf16x8*)(vsA + mt * 2048 + ((k2 * 64 + g * 16) ^ swz));
        acc0[mt] = __builtin_amdgcn_mfma_f32_16x16x32_bf16(a, p0, acc0[mt], 0, 0, 0);
        acc1[mt] = __builtin_amdgcn_mfma_f32_16x16x32_bf16(a, p1, acc1[mt], 0, 0, 0);
      }
    }
  }

  float inv0 = 1.f / accl0[0];
  float inv1 = 1.f / accl1[0];
  int b = bh >> 4, h = bh & 15;
  int sq = qt * 128 + wave * 32 + l15;
  unsigned short* orow0 = Out + ((size_t)(b * 1024 + sq) * 16 + h) * 128;
  unsigned short* orow1 = orow0 + (size_t)16 * 2048;
#pragma unroll
  for (int mt = 0; mt < 8; ++mt) {
    uint2 w0, w1;
    w0.x = cvt_pk_bf16(acc0[mt][0] * inv0, acc0[mt][1] * inv0);
    w0.y = cvt_pk_bf16(acc0[mt][2] * inv0, acc0[mt][3] * inv0);
    w1.x = cvt_pk_bf16(acc1[mt][0] * inv1, acc1[mt][1] * inv1);
    w1.y = cvt_pk_bf16(acc1[mt][2] * inv1, acc1[mt][3] * inv1);
    *(uint2*)(orow0 + mt * 16 + g * 4) = w0;
    *(uint2*)(orow1 + mt * 16 + g * 4) = w1;
  }
}

// ---------------------------------------------------------------------------
extern "C" void kernel_launch(void* const* d_in, const int* in_sizes, int n_in,
                              void* d_out, int out_size, void* d_ws, size_t ws_size,
                              hipStream_t stream) {
  const float* x       = (const float*)d_in[0];
  const float* cache_k = (const float*)d_in[1];
  const float* cache_v = (const float*)d_in[2];
  const float* w_qkv   = (const float*)d_in[3];
  const float* w_o     = (const float*)d_in[4];
  float* out = (float*)d_out;

  // workspace layout (~176.5 MiB)
  char* W = (char*)d_ws;
  constexpr size_t O_TRIG = 0;                       // 2 * 256KB
  constexpr size_t O_XB   = 524288;                  // 16MB (reused as attn_out)
  constexpr size_t O_WQT  = O_XB  + 16777216;        // 24MB
  constexpr size_t O_WOT  = O_WQT + 25165824;        // 8MB
  constexpr size_t O_QKV  = O_WOT + 8388608;         // 48MB
  constexpr size_t O_QB   = O_QKV + 50331648;        // 16MB
  constexpr size_t O_KF   = O_QB  + 16777216;        // 32MB
  constexpr size_t O_VT   = O_KF  + 33554432;        // 32MB
  float* cs_tab = (float*)(W + O_TRIG);
  float* sn_tab = (float*)(W + O_TRIG + 262144);
  unsigned short* xb   = (unsigned short*)(W + O_XB);
  unsigned short* wqT  = (unsigned short*)(W + O_WQT);
  unsigned short* woT  = (unsigned short*)(W + O_WOT);
  unsigned short* qkv  = (unsigned short*)(W + O_QKV);
  unsigned short* qb   = (unsigned short*)(W + O_QB);
  unsigned short* Kf   = (unsigned short*)(W + O_KF);
  unsigned short* Vt   = (unsigned short*)(W + O_VT);
  unsigned short* attn_out = xb;   // xb dead after gemm1

  build_trig<<<256, 256, 0, stream>>>(cs_tab, sn_tab);
  conv_bf16<<<4096, 256, 0, stream>>>(x, xb);                       // 8.4M elems
  transpose_conv<<<dim3(192, 64), 256, 0, stream>>>(w_qkv, wqT, 2048, 6144);
  transpose_conv<<<dim3(64, 64), 256, 0, stream>>>(w_o, woT, 2048, 2048);
  gemm_ring<4096, 6144, 2048, true><<<768, 512, 0, stream>>>(xb, wqT, qkv);
  rope_qk<<<4096, 256, 0, stream>>>(qkv, cs_tab, sn_tab, qb, Kf);
  copy_k<<<8192, 256, 0, stream>>>(cache_k, Kf);
  build_vt<<<dim3(64, 4, 64), 256, 0, stream>>>(cache_v, qkv, Vt);
  attn_kernel<<<512, 256, 0, stream>>>(qb, Kf, Vt, attn_out);
  gemm_ring<4096, 2048, 2048, false><<<256, 512, 0, stream>>>(attn_out, woT, out);
}